// Round 1
// baseline (1058.605 us; speedup 1.0000x reference)
//
#include <hip/hip_runtime.h>
#include <math.h>

// Problem constants: B=16, C=128, H=W=64, OUT=64, CR=16, RE=8
// Workspace layout (float elements):
static const size_t OFF_POOLED = 0;          // 2048
static const size_t OFF_WK     = 4096;       // 16*128*9 = 18432
static const size_t OFF_WC     = 32768;      // 256*128*9 = 294912
static const size_t OFF_T      = 524288;     // 16*128*64*64 = 8388608
static const size_t OFF_A      = OFF_T + 8388608;
static const size_t OFF_B      = OFF_A + 8388608;
static const size_t OFF_F      = OFF_B + 8388608;
// total = (OFF_F + 8388608) * 4 bytes = 136.3 MB

// ---------------- pooling: pooled[b*128+c] = mean over 64x64 ----------------
__global__ __launch_bounds__(256) void pool_mean_kernel(const float* __restrict__ x,
                                                        float* __restrict__ pooled) {
    int bc = blockIdx.x;  // 2048
    const float4* p = (const float4*)(x + (size_t)bc * 4096);
    float s = 0.f;
    for (int i = threadIdx.x; i < 1024; i += 256) {
        float4 v = p[i];
        s += v.x + v.y + v.z + v.w;
    }
    #pragma unroll
    for (int off = 32; off; off >>= 1) s += __shfl_down(s, off);
    __shared__ float r4[4];
    if ((threadIdx.x & 63) == 0) r4[threadIdx.x >> 6] = s;
    __syncthreads();
    if (threadIdx.x == 0) pooled[bc] = (r4[0] + r4[1] + r4[2] + r4[3]) * (1.f / 4096.f);
}

// ------------- wk: gelu(pooled@w1^T)@w2^T -> softmax over 9 -----------------
__global__ __launch_bounds__(128) void wk_kernel(const float* __restrict__ pooled,
                                                 const float* __restrict__ w1,   // [16,128]
                                                 const float* __restrict__ w2,   // [1152,16]
                                                 float* __restrict__ wk) {       // [16,128,9]
    int b = blockIdx.x;
    __shared__ float sp[128];
    __shared__ float sh[16];
    int t = threadIdx.x;
    sp[t] = pooled[b * 128 + t];
    __syncthreads();
    if (t < 16) {
        float acc = 0.f;
        #pragma unroll 4
        for (int c = 0; c < 128; c++) acc += w1[t * 128 + c] * sp[c];
        sh[t] = 0.5f * acc * (1.f + erff(acc * 0.70710678118654752f));  // exact gelu
    }
    __syncthreads();
    float lg[9];
    float m = -INFINITY;
    #pragma unroll
    for (int k = 0; k < 9; k++) {
        float acc = 0.f;
        const float* wr = w2 + (size_t)(t * 9 + k) * 16;
        #pragma unroll
        for (int r = 0; r < 16; r++) acc += wr[r] * sh[r];
        lg[k] = acc;
        m = fmaxf(m, acc);
    }
    float se = 0.f;
    #pragma unroll
    for (int k = 0; k < 9; k++) { lg[k] = expf(lg[k] - m); se += lg[k]; }
    float inv = 1.f / se;
    #pragma unroll
    for (int k = 0; k < 9; k++) wk[(size_t)(b * 128 + t) * 9 + k] = lg[k] * inv;
}

// -------- depthwise 3x3 with per-(b,c) kernel + residual (+relu+pool) -------
template <bool RELU_POOL>
__global__ __launch_bounds__(256) void dsc_apply_kernel(const float* __restrict__ x,
                                                        const float* __restrict__ wk,
                                                        float* __restrict__ y,
                                                        float* __restrict__ pooled_out) {
    int bc = blockIdx.x;  // 2048
    const float* xp = x + (size_t)bc * 4096;
    float* yp = y + (size_t)bc * 4096;
    __shared__ float tile[66 * 66];
    __shared__ float r4[4];
    int t = threadIdx.x;
    for (int i = t; i < 66 * 66; i += 256) tile[i] = 0.f;
    __syncthreads();
    for (int i = t; i < 4096; i += 256) {
        int h = i >> 6, w = i & 63;
        tile[(h + 1) * 66 + (w + 1)] = xp[i];
    }
    __syncthreads();
    float kk[9];
    #pragma unroll
    for (int k = 0; k < 9; k++) kk[k] = wk[(size_t)bc * 9 + k];
    float psum = 0.f;
    for (int i = t; i < 4096; i += 256) {
        int h = i >> 6, w = i & 63;
        const float* c = &tile[h * 66 + w];
        float v = kk[0] * c[0]   + kk[1] * c[1]   + kk[2] * c[2]
                + kk[3] * c[66]  + kk[4] * c[67]  + kk[5] * c[68]
                + kk[6] * c[132] + kk[7] * c[133] + kk[8] * c[134];
        v += c[67];  // residual (== xp[i])
        if (RELU_POOL) { v = fmaxf(v, 0.f); psum += v; }
        yp[i] = v;
    }
    if (RELU_POOL) {
        #pragma unroll
        for (int off = 32; off; off >>= 1) psum += __shfl_down(psum, off);
        if ((t & 63) == 0) r4[t >> 6] = psum;
        __syncthreads();
        if (t == 0) pooled_out[bc] = (r4[0] + r4[1] + r4[2] + r4[3]) * (1.f / 4096.f);
    }
}

// ------------- align: F[b,o,p] = sum_c W[o,c]*A + W[o,128+c]*B --------------
__global__ __launch_bounds__(256) void align_kernel(const float* __restrict__ A,
                                                    const float* __restrict__ Bv,
                                                    const float* __restrict__ W,  // [128,256]
                                                    float* __restrict__ F) {
    int b = blockIdx.z, ot = blockIdx.y, pt = blockIdx.x;
    int px = pt * 256 + threadIdx.x;
    __shared__ float sw[32 * 256];  // 32 KB
    for (int i = threadIdx.x; i < 32 * 256; i += 256) {
        int o = (ot << 5) + (i >> 8);
        int c = i & 255;
        sw[i] = W[(o << 8) + c];
    }
    __syncthreads();
    float acc[32];
    #pragma unroll
    for (int j = 0; j < 32; j++) acc[j] = 0.f;
    const float* ap = A + (size_t)b * 128 * 4096 + px;
    const float* bp = Bv + (size_t)b * 128 * 4096 + px;
    #pragma unroll 1
    for (int c = 0; c < 128; c += 4) {
        float x0 = ap[(size_t)c * 4096], x1 = ap[(size_t)(c + 1) * 4096];
        float x2 = ap[(size_t)(c + 2) * 4096], x3 = ap[(size_t)(c + 3) * 4096];
        #pragma unroll
        for (int j = 0; j < 32; j++) {
            float4 w4 = *(const float4*)&sw[j * 256 + c];
            acc[j] += w4.x * x0 + w4.y * x1 + w4.z * x2 + w4.w * x3;
        }
    }
    #pragma unroll 1
    for (int c = 0; c < 128; c += 4) {
        float x0 = bp[(size_t)c * 4096], x1 = bp[(size_t)(c + 1) * 4096];
        float x2 = bp[(size_t)(c + 2) * 4096], x3 = bp[(size_t)(c + 3) * 4096];
        #pragma unroll
        for (int j = 0; j < 32; j++) {
            float4 w4 = *(const float4*)&sw[j * 256 + 128 + c];
            acc[j] += w4.x * x0 + w4.y * x1 + w4.z * x2 + w4.w * x3;
        }
    }
    float* fp = F + ((size_t)b * 128 + (ot << 5)) * 4096 + px;
    #pragma unroll
    for (int j = 0; j < 32; j++) fp[(size_t)j * 4096] = acc[j];
}

// ---- combined weight: Wc[op][cin][tap] = sum_c up_w2[o,c]*up_w1[4c+ph,cin,tap]
__global__ __launch_bounds__(256) void wcomb_kernel(const float* __restrict__ w1,  // [512,128,3,3]
                                                    const float* __restrict__ w2,  // [64,128]
                                                    float* __restrict__ Wc) {      // [256,128,9]
    int idx = blockIdx.x * 256 + threadIdx.x;  // < 294912
    int tap = idx % 9;
    int cin = (idx / 9) % 128;
    int op = idx / (9 * 128);
    int o = op >> 2, ph = op & 3;
    float acc = 0.f;
    #pragma unroll 4
    for (int c = 0; c < 128; c++)
        acc += w2[o * 128 + c] * w1[((size_t)(c * 4 + ph) * 128 + cin) * 9 + tap];
    Wc[idx] = acc;
}

// --------------------- generic direct 3x3 conv (pad 1) ----------------------
// SHUFFLE: op = o*4 + (ry*2+rx); write out[b, o, 2h+ry, 2w+rx] (COUT/4 channels, 2Hx2W)
template <int CIN, int COUT, int H, int W, int CHUNK, int OT, int TH, int TW,
          int OPT, int PXPT, bool RELU, bool ACCUM, bool SHUFFLE>
__global__ __launch_bounds__(256) void conv3x3_kernel(const float* __restrict__ in,
                                                      const float* __restrict__ Wg,  // [COUT,CIN,9]
                                                      float* __restrict__ out) {
    constexpr int XROW = TW + 2;
    constexpr int XS = (TH + 2) * XROW;
    constexpr int WT = W / TW;
    constexpr int NPXG = (TH * TW) / PXPT;
    __shared__ float Xs[CHUNK * XS];
    __shared__ float Ws[CHUNK * 9 * OT];
    const int b = blockIdx.z;
    const int o0 = blockIdx.y * OT;
    const int tile = blockIdx.x;
    const int h0 = (tile / WT) * TH, w0 = (tile % WT) * TW;
    const int tid = threadIdx.x;
    const int pxg = tid % NPXG, og = tid / NPXG;
    const int p0 = pxg * PXPT;
    const int row = p0 / TW, colb = p0 % TW;

    float acc[OPT * PXPT];
    #pragma unroll
    for (int i = 0; i < OPT * PXPT; i++) acc[i] = 0.f;

    for (int c0 = 0; c0 < CIN; c0 += CHUNK) {
        for (int idx = tid; idx < CHUNK * XS; idx += 256) {
            int cin = idx / XS;
            int rem = idx - cin * XS;
            int r = rem / XROW, cc = rem - r * XROW;
            int gh = h0 - 1 + r, gw = w0 - 1 + cc;
            float v = 0.f;
            if (gh >= 0 && gh < H && gw >= 0 && gw < W)
                v = in[(((size_t)b * CIN + c0 + cin) * H + gh) * W + gw];
            Xs[idx] = v;
        }
        for (int idx = tid; idx < CHUNK * 9 * OT; idx += 256) {
            int o = idx % OT;
            int rem = idx / OT;
            int tap = rem % 9;
            int cin = rem / 9;
            Ws[idx] = Wg[((size_t)(o0 + o) * CIN + c0 + cin) * 9 + tap];
        }
        __syncthreads();
        #pragma unroll 1
        for (int cin = 0; cin < CHUNK; cin++) {
            const float* xr = &Xs[cin * XS + row * XROW + colb];
            const float* wr = &Ws[(cin * 9) * OT + og * OPT];
            #pragma unroll
            for (int kh = 0; kh < 3; kh++) {
                float xv[PXPT + 2];
                #pragma unroll
                for (int q = 0; q < PXPT + 2; q++) xv[q] = xr[kh * XROW + q];
                #pragma unroll
                for (int kw = 0; kw < 3; kw++) {
                    #pragma unroll
                    for (int j = 0; j < OPT; j++) {
                        float wv = wr[(kh * 3 + kw) * OT + j];
                        #pragma unroll
                        for (int i = 0; i < PXPT; i++) acc[j * PXPT + i] += wv * xv[kw + i];
                    }
                }
            }
        }
        __syncthreads();
    }
    #pragma unroll
    for (int j = 0; j < OPT; j++) {
        int op = o0 + og * OPT + j;
        #pragma unroll
        for (int i = 0; i < PXPT; i++) {
            float v = acc[j * PXPT + i];
            if (RELU) v = fmaxf(v, 0.f);
            size_t oi;
            if (SHUFFLE) {
                int o = op >> 2, ry = (op >> 1) & 1, rx = op & 1;
                int oy = 2 * (h0 + row) + ry, ox = 2 * (w0 + colb + i) + rx;
                oi = (((size_t)b * (COUT / 4) + o) * (2 * H) + oy) * (2 * W) + ox;
            } else {
                oi = (((size_t)b * COUT + op) * H + (h0 + row)) * W + (w0 + colb + i);
            }
            if (ACCUM) out[oi] += v;
            else out[oi] = v;
        }
    }
}

extern "C" void kernel_launch(void* const* d_in, const int* in_sizes, int n_in,
                              void* d_out, int out_size, void* d_ws, size_t ws_size,
                              hipStream_t stream) {
    const float* x1      = (const float*)d_in[0];
    const float* x2      = (const float*)d_in[1];
    const float* d1_w1   = (const float*)d_in[2];
    const float* d1_w2   = (const float*)d_in[3];
    const float* d2_w1   = (const float*)d_in[4];
    const float* d2_w2   = (const float*)d_in[5];
    const float* align_w = (const float*)d_in[6];
    const float* up_w1   = (const float*)d_in[7];
    const float* up_w2   = (const float*)d_in[8];
    const float* re_w1   = (const float*)d_in[9];
    const float* re_w2   = (const float*)d_in[10];
    float* out = (float*)d_out;
    float* ws  = (float*)d_ws;

    float* pooled = ws + OFF_POOLED;
    float* wk     = ws + OFF_WK;
    float* Wc     = ws + OFF_WC;
    float* bufT   = ws + OFF_T;
    float* bufA   = ws + OFF_A;
    float* bufB   = ws + OFF_B;
    float* bufF   = ws + OFF_F;
    float* bufR1  = ws + OFF_T;  // reuse T (dead by then)

    // Combined up-conv weight (independent of data path; launch first)
    wcomb_kernel<<<1152, 256, 0, stream>>>(up_w1, up_w2, Wc);

    for (int which = 0; which < 2; which++) {
        const float* x = which ? x2 : x1;
        float* dst = which ? bufB : bufA;
        pool_mean_kernel<<<2048, 256, 0, stream>>>(x, pooled);
        wk_kernel<<<16, 128, 0, stream>>>(pooled, d1_w1, d1_w2, wk);
        dsc_apply_kernel<true><<<2048, 256, 0, stream>>>(x, wk, bufT, pooled);
        wk_kernel<<<16, 128, 0, stream>>>(pooled, d2_w1, d2_w2, wk);
        dsc_apply_kernel<false><<<2048, 256, 0, stream>>>(bufT, wk, dst, nullptr);
    }

    align_kernel<<<dim3(16, 4, 16), 256, 0, stream>>>(bufA, bufB, align_w, bufF);

    // up-conv (fused conv3x3 + pixel_shuffle + 1x1): [16,128,64,64] -> out(up) [16,64,128,128]
    conv3x3_kernel<128, 256, 64, 64, 16, 32, 8, 32, 8, 4, false, false, true>
        <<<dim3(16, 8, 16), 256, 0, stream>>>(bufF, Wc, out);

    // re1: conv3x3(up) -> relu -> [16,8,128,128]
    conv3x3_kernel<64, 8, 128, 128, 16, 8, 4, 64, 4, 2, true, false, false>
        <<<dim3(64, 1, 16), 256, 0, stream>>>(out, re_w1, bufR1);

    // re2: conv3x3 -> accumulate into out (out = up + re)
    conv3x3_kernel<8, 64, 128, 128, 8, 32, 4, 64, 8, 4, false, true, false>
        <<<dim3(64, 2, 16), 256, 0, stream>>>(bufR1, re_w2, out);
}

// Round 2
// 564.211 us; speedup vs baseline: 1.8763x; 1.8763x over previous
//
#include <hip/hip_runtime.h>
#include <math.h>

// Problem constants: B=16, C=128, H=W=64, OUT=64, CR=16, RE=8
// Workspace layout (float elements):
static const size_t OFF_POOLED = 0;          // 2048
static const size_t OFF_WK     = 4096;       // 16*128*9 = 18432
static const size_t OFF_WC     = 32768;      // Wt bf16: 9*256*128 ushort = 589824 B
static const size_t OFF_T      = 524288;     // 16*128*64*64 = 8388608
static const size_t OFF_A      = OFF_T + 8388608;
static const size_t OFF_B      = OFF_A + 8388608;
static const size_t OFF_F      = OFF_B + 8388608;  // bf16 now (16.8 MB)

typedef short bf16x8 __attribute__((ext_vector_type(8)));
typedef float f32x16 __attribute__((ext_vector_type(16)));

static __device__ __forceinline__ unsigned short f2bf(float f) {
    unsigned int u = __builtin_bit_cast(unsigned int, f);
    u += 0x7FFF + ((u >> 16) & 1);  // RNE (finite inputs)
    return (unsigned short)(u >> 16);
}

// ---------------- pooling: pooled[b*128+c] = mean over 64x64 ----------------
__global__ __launch_bounds__(256) void pool_mean_kernel(const float* __restrict__ x,
                                                        float* __restrict__ pooled) {
    int bc = blockIdx.x;  // 2048
    const float4* p = (const float4*)(x + (size_t)bc * 4096);
    float s = 0.f;
    for (int i = threadIdx.x; i < 1024; i += 256) {
        float4 v = p[i];
        s += v.x + v.y + v.z + v.w;
    }
    #pragma unroll
    for (int off = 32; off; off >>= 1) s += __shfl_down(s, off);
    __shared__ float r4[4];
    if ((threadIdx.x & 63) == 0) r4[threadIdx.x >> 6] = s;
    __syncthreads();
    if (threadIdx.x == 0) pooled[bc] = (r4[0] + r4[1] + r4[2] + r4[3]) * (1.f / 4096.f);
}

// ------------- wk: gelu(pooled@w1^T)@w2^T -> softmax over 9 -----------------
__global__ __launch_bounds__(128) void wk_kernel(const float* __restrict__ pooled,
                                                 const float* __restrict__ w1,   // [16,128]
                                                 const float* __restrict__ w2,   // [1152,16]
                                                 float* __restrict__ wk) {       // [16,128,9]
    int b = blockIdx.x;
    __shared__ float sp[128];
    __shared__ float sh[16];
    int t = threadIdx.x;
    sp[t] = pooled[b * 128 + t];
    __syncthreads();
    if (t < 16) {
        float acc = 0.f;
        #pragma unroll 4
        for (int c = 0; c < 128; c++) acc += w1[t * 128 + c] * sp[c];
        sh[t] = 0.5f * acc * (1.f + erff(acc * 0.70710678118654752f));  // exact gelu
    }
    __syncthreads();
    float lg[9];
    float m = -INFINITY;
    #pragma unroll
    for (int k = 0; k < 9; k++) {
        float acc = 0.f;
        const float* wr = w2 + (size_t)(t * 9 + k) * 16;
        #pragma unroll
        for (int r = 0; r < 16; r++) acc += wr[r] * sh[r];
        lg[k] = acc;
        m = fmaxf(m, acc);
    }
    float se = 0.f;
    #pragma unroll
    for (int k = 0; k < 9; k++) { lg[k] = expf(lg[k] - m); se += lg[k]; }
    float inv = 1.f / se;
    #pragma unroll
    for (int k = 0; k < 9; k++) wk[(size_t)(b * 128 + t) * 9 + k] = lg[k] * inv;
}

// -------- depthwise 3x3 with per-(b,c) kernel + residual (+relu+pool) -------
template <bool RELU_POOL>
__global__ __launch_bounds__(256) void dsc_apply_kernel(const float* __restrict__ x,
                                                        const float* __restrict__ wk,
                                                        float* __restrict__ y,
                                                        float* __restrict__ pooled_out) {
    int bc = blockIdx.x;  // 2048
    const float* xp = x + (size_t)bc * 4096;
    float* yp = y + (size_t)bc * 4096;
    __shared__ float tile[66 * 66];
    __shared__ float r4[4];
    int t = threadIdx.x;
    for (int i = t; i < 66 * 66; i += 256) tile[i] = 0.f;
    __syncthreads();
    for (int i = t; i < 4096; i += 256) {
        int h = i >> 6, w = i & 63;
        tile[(h + 1) * 66 + (w + 1)] = xp[i];
    }
    __syncthreads();
    float kk[9];
    #pragma unroll
    for (int k = 0; k < 9; k++) kk[k] = wk[(size_t)bc * 9 + k];
    float psum = 0.f;
    for (int i = t; i < 4096; i += 256) {
        int h = i >> 6, w = i & 63;
        const float* c = &tile[h * 66 + w];
        float v = kk[0] * c[0]   + kk[1] * c[1]   + kk[2] * c[2]
                + kk[3] * c[66]  + kk[4] * c[67]  + kk[5] * c[68]
                + kk[6] * c[132] + kk[7] * c[133] + kk[8] * c[134];
        v += c[67];  // residual (== xp[i])
        if (RELU_POOL) { v = fmaxf(v, 0.f); psum += v; }
        yp[i] = v;
    }
    if (RELU_POOL) {
        #pragma unroll
        for (int off = 32; off; off >>= 1) psum += __shfl_down(psum, off);
        if ((t & 63) == 0) r4[t >> 6] = psum;
        __syncthreads();
        if (t == 0) pooled_out[bc] = (r4[0] + r4[1] + r4[2] + r4[3]) * (1.f / 4096.f);
    }
}

// ------------- align: F[b,o,p] = sum_c W[o,c]*A + W[o,128+c]*B  (bf16 out) --
__global__ __launch_bounds__(256) void align_kernel(const float* __restrict__ A,
                                                    const float* __restrict__ Bv,
                                                    const float* __restrict__ W,  // [128,256]
                                                    unsigned short* __restrict__ F) {
    int b = blockIdx.z, ot = blockIdx.y, pt = blockIdx.x;
    int px = pt * 256 + threadIdx.x;
    __shared__ float sw[32 * 256];  // 32 KB
    for (int i = threadIdx.x; i < 32 * 256; i += 256) {
        int o = (ot << 5) + (i >> 8);
        int c = i & 255;
        sw[i] = W[(o << 8) + c];
    }
    __syncthreads();
    float acc[32];
    #pragma unroll
    for (int j = 0; j < 32; j++) acc[j] = 0.f;
    const float* ap = A + (size_t)b * 128 * 4096 + px;
    const float* bp = Bv + (size_t)b * 128 * 4096 + px;
    #pragma unroll 1
    for (int c = 0; c < 128; c += 4) {
        float x0 = ap[(size_t)c * 4096], x1 = ap[(size_t)(c + 1) * 4096];
        float x2 = ap[(size_t)(c + 2) * 4096], x3 = ap[(size_t)(c + 3) * 4096];
        #pragma unroll
        for (int j = 0; j < 32; j++) {
            float4 w4 = *(const float4*)&sw[j * 256 + c];
            acc[j] += w4.x * x0 + w4.y * x1 + w4.z * x2 + w4.w * x3;
        }
    }
    #pragma unroll 1
    for (int c = 0; c < 128; c += 4) {
        float x0 = bp[(size_t)c * 4096], x1 = bp[(size_t)(c + 1) * 4096];
        float x2 = bp[(size_t)(c + 2) * 4096], x3 = bp[(size_t)(c + 3) * 4096];
        #pragma unroll
        for (int j = 0; j < 32; j++) {
            float4 w4 = *(const float4*)&sw[j * 256 + 128 + c];
            acc[j] += w4.x * x0 + w4.y * x1 + w4.z * x2 + w4.w * x3;
        }
    }
    unsigned short* fp = F + ((size_t)b * 128 + (ot << 5)) * 4096 + px;
    #pragma unroll
    for (int j = 0; j < 32; j++) fp[(size_t)j * 4096] = f2bf(acc[j]);
}

// ---- combined up weight, bf16, tap-major: Wt[tap][op][cin] -----------------
__global__ __launch_bounds__(256) void wcomb_kernel(const float* __restrict__ w1,  // [512,128,3,3]
                                                    const float* __restrict__ w2,  // [64,128]
                                                    unsigned short* __restrict__ Wt) {
    int idx = blockIdx.x * 256 + threadIdx.x;  // < 294912 = 9*256*128
    int cin = idx & 127;
    int op = (idx >> 7) & 255;
    int tap = idx >> 15;
    int o = op >> 2, ph = op & 3;
    float acc = 0.f;
    #pragma unroll 4
    for (int c = 0; c < 128; c++)
        acc += w2[o * 128 + c] * w1[((size_t)(c * 4 + ph) * 128 + cin) * 9 + tap];
    Wt[idx] = f2bf(acc);
}

// ------ up-conv: implicit GEMM, bf16 MFMA 32x32x16, fused pixel-shuffle -----
// out[b, op=256, h, w] = sum_{tap,cin} Wt[tap,op,cin]*F[b,cin,h+dy,w+dx], shuffled store.
// Block: 256 op x (16x8 px) tile. 4 waves, each 64 op x 128 px (2m x 4n MFMA tiles).
__global__ __launch_bounds__(256, 2) void up_mfma_kernel(const unsigned short* __restrict__ F,
                                                         const unsigned short* __restrict__ Wt,
                                                         float* __restrict__ out) {
    __shared__ unsigned short Xs[180 * 72];        // halo 18x10, 64 cin, pad-stride 72
    __shared__ unsigned short Ws[2][4 * 256 * 8];  // [k8][op][8cin], double-buffered
    const int b = blockIdx.y;
    const int tr = blockIdx.x >> 3, tc = blockIdx.x & 7;
    const int tid = threadIdx.x;
    const int wave = tid >> 6, lane = tid & 63;
    const int l31 = lane & 31, half = lane >> 5;

    f32x16 acc[2][4];
    #pragma unroll
    for (int mt = 0; mt < 2; mt++)
        #pragma unroll
        for (int nt = 0; nt < 4; nt++)
            #pragma unroll
            for (int r = 0; r < 16; r++) acc[mt][nt][r] = 0.f;

    int xbase[4];
    #pragma unroll
    for (int nt = 0; nt < 4; nt++) {
        int rowl = nt * 4 + (l31 >> 3);
        int coll = l31 & 7;
        xbase[nt] = (rowl * 10 + coll) * 72 + half * 8;
    }
    const int abase0 = (wave * 64 + l31) * 8 + half * 2048;
    const int abase1 = abase0 + 256;  // +32 op

    bf16x8 wreg[4];
    #pragma unroll
    for (int k8 = 0; k8 < 4; k8++)  // preload i=0: tap0, chunk0
        wreg[k8] = *(const bf16x8*)(Wt + (size_t)tid * 128 + k8 * 8);

    for (int i = 0; i < 36; i++) {
        const int xc = i / 18;
        const int j = i - xc * 18;
        const int wc = j & 1;
        const int tap = j >> 1;
        const int buf = i & 1;
        if (j == 0) {
            if (i) __syncthreads();  // old Xs reads done
            for (int idx = tid; idx < 180 * 64; idx += 256) {
                int cl = idx / 180;
                int px = idx - cl * 180;
                int r = px / 10, c = px - r * 10;
                int gh = tr * 16 - 1 + r, gw = tc * 8 - 1 + c;
                unsigned short v = 0;
                if (gh >= 0 && gh < 64 && gw >= 0 && gw < 64)
                    v = F[((size_t)(b * 128 + xc * 64 + cl) << 12) + (gh << 6) + gw];
                Xs[px * 72 + cl] = v;
            }
        }
        #pragma unroll
        for (int k8 = 0; k8 < 4; k8++)
            *(bf16x8*)&Ws[buf][(k8 * 256 + tid) * 8] = wreg[k8];
        if (i + 1 < 36) {  // prefetch W(i+1)
            int i2 = i + 1;
            int xc2 = i2 / 18;
            int j2 = i2 - xc2 * 18;
            int tap2 = j2 >> 1;
            int ch2 = xc2 * 2 + (j2 & 1);
            const unsigned short* src = Wt + ((size_t)(tap2 * 256 + tid) << 7) + ch2 * 32;
            #pragma unroll
            for (int k8 = 0; k8 < 4; k8++) wreg[k8] = *(const bf16x8*)(src + k8 * 8);
        }
        __syncthreads();
        const int ky = tap / 3;
        const int xoff = (ky * 10 + (tap - ky * 3)) * 72 + wc * 32;
        #pragma unroll
        for (int s = 0; s < 2; s++) {
            bf16x8 a0 = *(const bf16x8*)&Ws[buf][abase0 + s * 4096];
            bf16x8 a1 = *(const bf16x8*)&Ws[buf][abase1 + s * 4096];
            #pragma unroll
            for (int nt = 0; nt < 4; nt++) {
                bf16x8 bv = *(const bf16x8*)&Xs[xbase[nt] + xoff + s * 16];
                acc[0][nt] = __builtin_amdgcn_mfma_f32_32x32x16_bf16(a0, bv, acc[0][nt], 0, 0, 0);
                acc[1][nt] = __builtin_amdgcn_mfma_f32_32x32x16_bf16(a1, bv, acc[1][nt], 0, 0, 0);
            }
        }
    }
    // epilogue: C/D layout col=lane&31, row=(r&3)+8*(r>>2)+4*half; shuffled store
    const size_t ob = (size_t)b * 64 * 128 * 128;
    const int h0 = tr * 16, w0 = tc * 8;
    #pragma unroll
    for (int mt = 0; mt < 2; mt++) {
        int opb = wave * 64 + mt * 32 + half * 4;
        #pragma unroll
        for (int nt = 0; nt < 4; nt++) {
            int px = nt * 32 + l31;
            int h = h0 + (px >> 3), w = w0 + (px & 7);
            #pragma unroll
            for (int r = 0; r < 16; r++) {
                int op = opb + (r & 3) + ((r >> 2) << 3);
                int o = op >> 2, ry = (op >> 1) & 1, rx = op & 1;
                out[ob + (((size_t)o << 7) + (h << 1) + ry) * 128 + (w << 1) + rx] =
                    acc[mt][nt][r];
            }
        }
    }
}

// --------------------- generic direct 3x3 conv (pad 1) ----------------------
template <int CIN, int COUT, int H, int W, int CHUNK, int OT, int TH, int TW,
          int OPT, int PXPT, bool RELU, bool ACCUM>
__global__ __launch_bounds__(256) void conv3x3_kernel(const float* __restrict__ in,
                                                      const float* __restrict__ Wg,  // [COUT,CIN,9]
                                                      float* __restrict__ out) {
    constexpr int XROW = TW + 2;
    constexpr int XS = (TH + 2) * XROW;
    constexpr int WT = W / TW;
    constexpr int NPXG = (TH * TW) / PXPT;
    __shared__ float Xs[CHUNK * XS];
    __shared__ float Ws[CHUNK * 9 * OT];
    const int b = blockIdx.z;
    const int o0 = blockIdx.y * OT;
    const int tile = blockIdx.x;
    const int h0 = (tile / WT) * TH, w0 = (tile % WT) * TW;
    const int tid = threadIdx.x;
    const int pxg = tid % NPXG, og = tid / NPXG;
    const int p0 = pxg * PXPT;
    const int row = p0 / TW, colb = p0 % TW;

    float acc[OPT * PXPT];
    #pragma unroll
    for (int i = 0; i < OPT * PXPT; i++) acc[i] = 0.f;

    for (int c0 = 0; c0 < CIN; c0 += CHUNK) {
        for (int idx = tid; idx < CHUNK * XS; idx += 256) {
            int cin = idx / XS;
            int rem = idx - cin * XS;
            int r = rem / XROW, cc = rem - r * XROW;
            int gh = h0 - 1 + r, gw = w0 - 1 + cc;
            float v = 0.f;
            if (gh >= 0 && gh < H && gw >= 0 && gw < W)
                v = in[(((size_t)b * CIN + c0 + cin) * H + gh) * W + gw];
            Xs[idx] = v;
        }
        for (int idx = tid; idx < CHUNK * 9 * OT; idx += 256) {
            int o = idx % OT;
            int rem = idx / OT;
            int tap = rem % 9;
            int cin = rem / 9;
            Ws[idx] = Wg[((size_t)(o0 + o) * CIN + c0 + cin) * 9 + tap];
        }
        __syncthreads();
        #pragma unroll 1
        for (int cin = 0; cin < CHUNK; cin++) {
            const float* xr = &Xs[cin * XS + row * XROW + colb];
            const float* wr = &Ws[(cin * 9) * OT + og * OPT];
            #pragma unroll
            for (int kh = 0; kh < 3; kh++) {
                float xv[PXPT + 2];
                #pragma unroll
                for (int q = 0; q < PXPT + 2; q++) xv[q] = xr[kh * XROW + q];
                #pragma unroll
                for (int kw = 0; kw < 3; kw++) {
                    #pragma unroll
                    for (int j = 0; j < OPT; j++) {
                        float wv = wr[(kh * 3 + kw) * OT + j];
                        #pragma unroll
                        for (int i = 0; i < PXPT; i++) acc[j * PXPT + i] += wv * xv[kw + i];
                    }
                }
            }
        }
        __syncthreads();
    }
    #pragma unroll
    for (int j = 0; j < OPT; j++) {
        int op = o0 + og * OPT + j;
        #pragma unroll
        for (int i = 0; i < PXPT; i++) {
            float v = acc[j * PXPT + i];
            if (RELU) v = fmaxf(v, 0.f);
            size_t oi = (((size_t)b * COUT + op) * H + (h0 + row)) * W + (w0 + colb + i);
            if (ACCUM) out[oi] += v;
            else out[oi] = v;
        }
    }
}

extern "C" void kernel_launch(void* const* d_in, const int* in_sizes, int n_in,
                              void* d_out, int out_size, void* d_ws, size_t ws_size,
                              hipStream_t stream) {
    const float* x1      = (const float*)d_in[0];
    const float* x2      = (const float*)d_in[1];
    const float* d1_w1   = (const float*)d_in[2];
    const float* d1_w2   = (const float*)d_in[3];
    const float* d2_w1   = (const float*)d_in[4];
    const float* d2_w2   = (const float*)d_in[5];
    const float* align_w = (const float*)d_in[6];
    const float* up_w1   = (const float*)d_in[7];
    const float* up_w2   = (const float*)d_in[8];
    const float* re_w1   = (const float*)d_in[9];
    const float* re_w2   = (const float*)d_in[10];
    float* out = (float*)d_out;
    float* ws  = (float*)d_ws;

    float* pooled = ws + OFF_POOLED;
    float* wk     = ws + OFF_WK;
    unsigned short* Wt   = (unsigned short*)(ws + OFF_WC);
    float* bufT   = ws + OFF_T;
    float* bufA   = ws + OFF_A;
    float* bufB   = ws + OFF_B;
    unsigned short* bufF = (unsigned short*)(ws + OFF_F);
    float* bufR1  = ws + OFF_T;  // reuse T (dead by then)

    wcomb_kernel<<<1152, 256, 0, stream>>>(up_w1, up_w2, Wt);

    for (int which = 0; which < 2; which++) {
        const float* x = which ? x2 : x1;
        float* dst = which ? bufB : bufA;
        pool_mean_kernel<<<2048, 256, 0, stream>>>(x, pooled);
        wk_kernel<<<16, 128, 0, stream>>>(pooled, d1_w1, d1_w2, wk);
        dsc_apply_kernel<true><<<2048, 256, 0, stream>>>(x, wk, bufT, pooled);
        wk_kernel<<<16, 128, 0, stream>>>(pooled, d2_w1, d2_w2, wk);
        dsc_apply_kernel<false><<<2048, 256, 0, stream>>>(bufT, wk, dst, nullptr);
    }

    align_kernel<<<dim3(16, 4, 16), 256, 0, stream>>>(bufA, bufB, align_w, bufF);

    // up-conv (conv3x3 + pixel_shuffle + 1x1 fused) via bf16 MFMA implicit GEMM
    up_mfma_kernel<<<dim3(32, 16), 256, 0, stream>>>(bufF, Wt, out);

    // re1: conv3x3(up) -> relu -> [16,8,128,128]
    conv3x3_kernel<64, 8, 128, 128, 16, 8, 4, 64, 4, 2, true, false>
        <<<dim3(64, 1, 16), 256, 0, stream>>>(out, re_w1, bufR1);

    // re2: conv3x3 -> accumulate into out (out = up + re)
    conv3x3_kernel<8, 64, 128, 128, 8, 32, 4, 64, 8, 4, false, true>
        <<<dim3(64, 2, 16), 256, 0, stream>>>(bufR1, re_w2, out);
}

// Round 3
// 485.885 us; speedup vs baseline: 2.1787x; 1.1612x over previous
//
#include <hip/hip_runtime.h>
#include <math.h>

// Problem constants: B=16, C=128, H=W=64, OUT=64, CR=16, RE=8
// Workspace layout (float elements):
static const size_t OFF_POOLED = 0;          // 2048
static const size_t OFF_WK     = 4096;       // 16*128*9
static const size_t OFF_WC     = 32768;      // Wt bf16: 294912 ushort = 147456 f
static const size_t OFF_WA     = 180224;     // Wf bf16: 32768 ushort = 16384 f
static const size_t OFF_T      = 524288;     // bufT bf16 (or bufR1 f32 later)
static const size_t OFF_A      = OFF_T + 4194304;   // bf16
static const size_t OFF_B      = OFF_A + 4194304;   // bf16
static const size_t OFF_F      = OFF_B + 4194304;   // bf16

typedef short bf16x8 __attribute__((ext_vector_type(8)));
typedef float f32x16 __attribute__((ext_vector_type(16)));

static __device__ __forceinline__ unsigned short f2bf(float f) {
    unsigned int u = __builtin_bit_cast(unsigned int, f);
    u += 0x7FFF + ((u >> 16) & 1);  // RNE (finite inputs)
    return (unsigned short)(u >> 16);
}
static __device__ __forceinline__ float bf2f(unsigned short u) {
    return __builtin_bit_cast(float, ((unsigned int)u) << 16);
}
static __device__ __forceinline__ float ldf(float v) { return v; }
static __device__ __forceinline__ float ldf(unsigned short v) { return bf2f(v); }
static __device__ __forceinline__ void stf(float* p, float v) { *p = v; }
static __device__ __forceinline__ void stf(unsigned short* p, float v) { *p = f2bf(v); }

// ---------------- pooling: pooled[b*128+c] = mean over 64x64 ----------------
__global__ __launch_bounds__(256) void pool_mean_kernel(const float* __restrict__ x,
                                                        float* __restrict__ pooled) {
    int bc = blockIdx.x;  // 2048
    const float4* p = (const float4*)(x + (size_t)bc * 4096);
    float s = 0.f;
    for (int i = threadIdx.x; i < 1024; i += 256) {
        float4 v = p[i];
        s += v.x + v.y + v.z + v.w;
    }
    #pragma unroll
    for (int off = 32; off; off >>= 1) s += __shfl_down(s, off);
    __shared__ float r4[4];
    if ((threadIdx.x & 63) == 0) r4[threadIdx.x >> 6] = s;
    __syncthreads();
    if (threadIdx.x == 0) pooled[bc] = (r4[0] + r4[1] + r4[2] + r4[3]) * (1.f / 4096.f);
}

// ------------- wk: gelu(pooled@w1^T)@w2^T -> softmax over 9 -----------------
__global__ __launch_bounds__(128) void wk_kernel(const float* __restrict__ pooled,
                                                 const float* __restrict__ w1,   // [16,128]
                                                 const float* __restrict__ w2,   // [1152,16]
                                                 float* __restrict__ wk) {       // [16,128,9]
    int b = blockIdx.x;
    __shared__ float sp[128];
    __shared__ float sh[16];
    int t = threadIdx.x;
    sp[t] = pooled[b * 128 + t];
    __syncthreads();
    if (t < 16) {
        float acc = 0.f;
        #pragma unroll 4
        for (int c = 0; c < 128; c++) acc += w1[t * 128 + c] * sp[c];
        sh[t] = 0.5f * acc * (1.f + erff(acc * 0.70710678118654752f));  // exact gelu
    }
    __syncthreads();
    float lg[9];
    float m = -INFINITY;
    #pragma unroll
    for (int k = 0; k < 9; k++) {
        float acc = 0.f;
        const float* wr = w2 + (size_t)(t * 9 + k) * 16;
        #pragma unroll
        for (int r = 0; r < 16; r++) acc += wr[r] * sh[r];
        lg[k] = acc;
        m = fmaxf(m, acc);
    }
    float se = 0.f;
    #pragma unroll
    for (int k = 0; k < 9; k++) { lg[k] = expf(lg[k] - m); se += lg[k]; }
    float inv = 1.f / se;
    #pragma unroll
    for (int k = 0; k < 9; k++) wk[(size_t)(b * 128 + t) * 9 + k] = lg[k] * inv;
}

// -------- depthwise 3x3 with per-(b,c) kernel + residual (+relu+pool) -------
template <typename Tin, typename Tout, bool RELU_POOL>
__global__ __launch_bounds__(256) void dsc_apply_kernel(const Tin* __restrict__ x,
                                                        const float* __restrict__ wk,
                                                        Tout* __restrict__ y,
                                                        float* __restrict__ pooled_out) {
    int bc = blockIdx.x;  // 2048
    const Tin* xp = x + (size_t)bc * 4096;
    Tout* yp = y + (size_t)bc * 4096;
    __shared__ float tile[66 * 66];
    __shared__ float r4[4];
    int t = threadIdx.x;
    for (int i = t; i < 66 * 66; i += 256) tile[i] = 0.f;
    __syncthreads();
    for (int i = t; i < 4096; i += 256) {
        int h = i >> 6, w = i & 63;
        tile[(h + 1) * 66 + (w + 1)] = ldf(xp[i]);
    }
    __syncthreads();
    float kk[9];
    #pragma unroll
    for (int k = 0; k < 9; k++) kk[k] = wk[(size_t)bc * 9 + k];
    float psum = 0.f;
    for (int i = t; i < 4096; i += 256) {
        int h = i >> 6, w = i & 63;
        const float* c = &tile[h * 66 + w];
        float v = kk[0] * c[0]   + kk[1] * c[1]   + kk[2] * c[2]
                + kk[3] * c[66]  + kk[4] * c[67]  + kk[5] * c[68]
                + kk[6] * c[132] + kk[7] * c[133] + kk[8] * c[134];
        v += c[67];  // residual
        if (RELU_POOL) { v = fmaxf(v, 0.f); psum += v; }
        stf(&yp[i], v);
    }
    if (RELU_POOL) {
        #pragma unroll
        for (int off = 32; off; off >>= 1) psum += __shfl_down(psum, off);
        if ((t & 63) == 0) r4[t >> 6] = psum;
        __syncthreads();
        if (t == 0) pooled_out[bc] = (r4[0] + r4[1] + r4[2] + r4[3]) * (1.f / 4096.f);
    }
}

// ---- align weight prep: Wf in A-fragment order [step(16)][mt(4)][lane(64)][8]
__global__ __launch_bounds__(256) void awprep_kernel(const float* __restrict__ W,  // [128,256]
                                                     unsigned short* __restrict__ Wf) {
    int t = threadIdx.x;
    #pragma unroll 1
    for (int i = 0; i < 16; i++) {
        int tk = t + (i << 8);
        int step = tk >> 8, mt = (tk >> 6) & 3, lane = tk & 63;
        int o = mt * 32 + (lane & 31);
        int cb = step * 16 + (lane >> 5) * 8;
        #pragma unroll
        for (int j = 0; j < 8; j++) Wf[(size_t)tk * 8 + j] = f2bf(W[o * 256 + cb + j]);
    }
}

// ---- align: F[b,o,px] = sum_c W[o,c]*concat(A,B)[c,px], bf16 MFMA ----------
// Block: M=128 (all o), N=128 px; 4 waves, each full-M x 32 px.
__global__ __launch_bounds__(256, 2) void align_mfma_kernel(const unsigned short* __restrict__ A,
                                                            const unsigned short* __restrict__ Bv,
                                                            const unsigned short* __restrict__ Wf,
                                                            unsigned short* __restrict__ F) {
    __shared__ unsigned short Xs[2 * 128 * 8];  // [k-half][px][8c], 4 KB
    const int b = blockIdx.y;
    const int px0 = blockIdx.x << 7;
    const int tid = threadIdx.x;
    const int wave = tid >> 6, lane = tid & 63;
    const int l31 = lane & 31, half = lane >> 5;

    f32x16 acc[4];
    #pragma unroll
    for (int mt = 0; mt < 4; mt++)
        #pragma unroll
        for (int r = 0; r < 16; r++) acc[mt][r] = 0.f;

    const int cg0 = tid >> 7, pxs0 = tid & 127;       // staging task 0
    const int bfofs = (wave * 32 + l31) * 8 + half * 1024;

    for (int step = 0; step < 16; step++) {
        const unsigned short* src =
            (step < 8 ? A : Bv) + (((size_t)(b * 128 + (step & 7) * 16)) << 12) + px0;
        if (step) __syncthreads();  // previous reads done
        #pragma unroll
        for (int q = 0; q < 2; q++) {
            int cg = cg0 + q * 2, px = pxs0;
            unsigned short v0 = src[((size_t)(cg * 4 + 0) << 12) + px];
            unsigned short v1 = src[((size_t)(cg * 4 + 1) << 12) + px];
            unsigned short v2 = src[((size_t)(cg * 4 + 2) << 12) + px];
            unsigned short v3 = src[((size_t)(cg * 4 + 3) << 12) + px];
            ushort4 pk = {v0, v1, v2, v3};
            *(ushort4*)&Xs[(cg >> 1) * 1024 + px * 8 + (cg & 1) * 4] = pk;
        }
        __syncthreads();
        bf16x8 bfrag = *(const bf16x8*)&Xs[bfofs];
        const bf16x8* wf = (const bf16x8*)(Wf + ((size_t)step * 4 * 64 + lane) * 8);
        #pragma unroll
        for (int mt = 0; mt < 4; mt++) {
            bf16x8 afrag = wf[mt * 64 >> 0];  // (step*4+mt)*64 + lane, each 8 elems
            acc[mt] = __builtin_amdgcn_mfma_f32_32x32x16_bf16(afrag, bfrag, acc[mt], 0, 0, 0);
        }
    }
    // epilogue: row=(r&3)+8*(r>>2)+4*half (=o within mt*32), col=l31 (=px within wave*32)
    unsigned short* fp = F + (((size_t)b * 128) << 12) + px0 + wave * 32 + l31;
    #pragma unroll
    for (int mt = 0; mt < 4; mt++) {
        #pragma unroll
        for (int r = 0; r < 16; r++) {
            int o = mt * 32 + (r & 3) + ((r >> 2) << 3) + half * 4;
            fp[(size_t)o << 12] = f2bf(acc[mt][r]);
        }
    }
}

// ---- combined up weight, bf16, tap-major: Wt[tap][op][cin] -----------------
__global__ __launch_bounds__(256) void wcomb_kernel(const float* __restrict__ w1,  // [512,128,3,3]
                                                    const float* __restrict__ w2,  // [64,128]
                                                    unsigned short* __restrict__ Wt) {
    int idx = blockIdx.x * 256 + threadIdx.x;  // < 294912 = 9*256*128
    int cin = idx & 127;
    int op = (idx >> 7) & 255;
    int tap = idx >> 15;
    int o = op >> 2, ph = op & 3;
    float acc = 0.f;
    #pragma unroll 4
    for (int c = 0; c < 128; c++)
        acc += w2[o * 128 + c] * w1[((size_t)(c * 4 + ph) * 128 + cin) * 9 + tap];
    Wt[idx] = f2bf(acc);
}

// ------ up-conv: implicit GEMM, bf16 MFMA 32x32x16, fused pixel-shuffle -----
__global__ __launch_bounds__(256, 2) void up_mfma_kernel(const unsigned short* __restrict__ F,
                                                         const unsigned short* __restrict__ Wt,
                                                         float* __restrict__ out) {
    __shared__ unsigned short Xs[180 * 72];        // halo 18x10, 64 cin, pad-stride 72
    __shared__ unsigned short Ws[2][4 * 256 * 8];  // [k8][op][8cin], double-buffered
    const int b = blockIdx.y;
    const int tr = blockIdx.x >> 3, tc = blockIdx.x & 7;
    const int tid = threadIdx.x;
    const int wave = tid >> 6, lane = tid & 63;
    const int l31 = lane & 31, half = lane >> 5;

    f32x16 acc[2][4];
    #pragma unroll
    for (int mt = 0; mt < 2; mt++)
        #pragma unroll
        for (int nt = 0; nt < 4; nt++)
            #pragma unroll
            for (int r = 0; r < 16; r++) acc[mt][nt][r] = 0.f;

    int xbase[4];
    #pragma unroll
    for (int nt = 0; nt < 4; nt++) {
        int rowl = nt * 4 + (l31 >> 3);
        int coll = l31 & 7;
        xbase[nt] = (rowl * 10 + coll) * 72 + half * 8;
    }
    const int abase0 = (wave * 64 + l31) * 8 + half * 2048;
    const int abase1 = abase0 + 256;  // +32 op

    bf16x8 wreg[4];
    #pragma unroll
    for (int k8 = 0; k8 < 4; k8++)  // preload i=0: tap0, chunk0
        wreg[k8] = *(const bf16x8*)(Wt + (size_t)tid * 128 + k8 * 8);

    for (int i = 0; i < 36; i++) {
        const int xc = i / 18;
        const int j = i - xc * 18;
        const int wc = j & 1;
        const int tap = j >> 1;
        const int buf = i & 1;
        if (j == 0) {
            if (i) __syncthreads();  // old Xs reads done
            for (int idx = tid; idx < 180 * 64; idx += 256) {
                int cl = idx / 180;
                int px = idx - cl * 180;
                int r = px / 10, c = px - r * 10;
                int gh = tr * 16 - 1 + r, gw = tc * 8 - 1 + c;
                unsigned short v = 0;
                if (gh >= 0 && gh < 64 && gw >= 0 && gw < 64)
                    v = F[((size_t)(b * 128 + xc * 64 + cl) << 12) + (gh << 6) + gw];
                Xs[px * 72 + cl] = v;
            }
        }
        #pragma unroll
        for (int k8 = 0; k8 < 4; k8++)
            *(bf16x8*)&Ws[buf][(k8 * 256 + tid) * 8] = wreg[k8];
        if (i + 1 < 36) {  // prefetch W(i+1)
            int i2 = i + 1;
            int xc2 = i2 / 18;
            int j2 = i2 - xc2 * 18;
            int tap2 = j2 >> 1;
            int ch2 = xc2 * 2 + (j2 & 1);
            const unsigned short* src = Wt + ((size_t)(tap2 * 256 + tid) << 7) + ch2 * 32;
            #pragma unroll
            for (int k8 = 0; k8 < 4; k8++) wreg[k8] = *(const bf16x8*)(src + k8 * 8);
        }
        __syncthreads();
        const int ky = tap / 3;
        const int xoff = (ky * 10 + (tap - ky * 3)) * 72 + wc * 32;
        #pragma unroll
        for (int s = 0; s < 2; s++) {
            bf16x8 a0 = *(const bf16x8*)&Ws[buf][abase0 + s * 4096];
            bf16x8 a1 = *(const bf16x8*)&Ws[buf][abase1 + s * 4096];
            #pragma unroll
            for (int nt = 0; nt < 4; nt++) {
                bf16x8 bv = *(const bf16x8*)&Xs[xbase[nt] + xoff + s * 16];
                acc[0][nt] = __builtin_amdgcn_mfma_f32_32x32x16_bf16(a0, bv, acc[0][nt], 0, 0, 0);
                acc[1][nt] = __builtin_amdgcn_mfma_f32_32x32x16_bf16(a1, bv, acc[1][nt], 0, 0, 0);
            }
        }
    }
    const size_t ob = (size_t)b * 64 * 128 * 128;
    const int h0 = tr * 16, w0 = tc * 8;
    #pragma unroll
    for (int mt = 0; mt < 2; mt++) {
        int opb = wave * 64 + mt * 32 + half * 4;
        #pragma unroll
        for (int nt = 0; nt < 4; nt++) {
            int px = nt * 32 + l31;
            int h = h0 + (px >> 3), w = w0 + (px & 7);
            #pragma unroll
            for (int r = 0; r < 16; r++) {
                int op = opb + (r & 3) + ((r >> 2) << 3);
                int o = op >> 2, ry = (op >> 1) & 1, rx = op & 1;
                out[ob + (((size_t)o << 7) + (h << 1) + ry) * 128 + (w << 1) + rx] =
                    acc[mt][nt][r];
            }
        }
    }
}

// --------------------- generic direct 3x3 conv (pad 1) ----------------------
template <int CIN, int COUT, int H, int W, int CHUNK, int OT, int TH, int TW,
          int OPT, int PXPT, bool RELU, bool ACCUM>
__global__ __launch_bounds__(256) void conv3x3_kernel(const float* __restrict__ in,
                                                      const float* __restrict__ Wg,  // [COUT,CIN,9]
                                                      float* __restrict__ out) {
    constexpr int XROW = TW + 2;
    constexpr int XS = (TH + 2) * XROW;
    constexpr int WT = W / TW;
    constexpr int NPXG = (TH * TW) / PXPT;
    __shared__ float Xs[CHUNK * XS];
    __shared__ float Ws[CHUNK * 9 * OT];
    const int b = blockIdx.z;
    const int o0 = blockIdx.y * OT;
    const int tile = blockIdx.x;
    const int h0 = (tile / WT) * TH, w0 = (tile % WT) * TW;
    const int tid = threadIdx.x;
    const int pxg = tid % NPXG, og = tid / NPXG;
    const int p0 = pxg * PXPT;
    const int row = p0 / TW, colb = p0 % TW;

    float acc[OPT * PXPT];
    #pragma unroll
    for (int i = 0; i < OPT * PXPT; i++) acc[i] = 0.f;

    for (int c0 = 0; c0 < CIN; c0 += CHUNK) {
        for (int idx = tid; idx < CHUNK * XS; idx += 256) {
            int cin = idx / XS;
            int rem = idx - cin * XS;
            int r = rem / XROW, cc = rem - r * XROW;
            int gh = h0 - 1 + r, gw = w0 - 1 + cc;
            float v = 0.f;
            if (gh >= 0 && gh < H && gw >= 0 && gw < W)
                v = in[(((size_t)b * CIN + c0 + cin) * H + gh) * W + gw];
            Xs[idx] = v;
        }
        for (int idx = tid; idx < CHUNK * 9 * OT; idx += 256) {
            int o = idx % OT;
            int rem = idx / OT;
            int tap = rem % 9;
            int cin = rem / 9;
            Ws[idx] = Wg[((size_t)(o0 + o) * CIN + c0 + cin) * 9 + tap];
        }
        __syncthreads();
        #pragma unroll 1
        for (int cin = 0; cin < CHUNK; cin++) {
            const float* xr = &Xs[cin * XS + row * XROW + colb];
            const float* wr = &Ws[(cin * 9) * OT + og * OPT];
            #pragma unroll
            for (int kh = 0; kh < 3; kh++) {
                float xv[PXPT + 2];
                #pragma unroll
                for (int q = 0; q < PXPT + 2; q++) xv[q] = xr[kh * XROW + q];
                #pragma unroll
                for (int kw = 0; kw < 3; kw++) {
                    #pragma unroll
                    for (int j = 0; j < OPT; j++) {
                        float wv = wr[(kh * 3 + kw) * OT + j];
                        #pragma unroll
                        for (int i = 0; i < PXPT; i++) acc[j * PXPT + i] += wv * xv[kw + i];
                    }
                }
            }
        }
        __syncthreads();
    }
    #pragma unroll
    for (int j = 0; j < OPT; j++) {
        int op = o0 + og * OPT + j;
        #pragma unroll
        for (int i = 0; i < PXPT; i++) {
            float v = acc[j * PXPT + i];
            if (RELU) v = fmaxf(v, 0.f);
            size_t oi = (((size_t)b * COUT + op) * H + (h0 + row)) * W + (w0 + colb + i);
            if (ACCUM) out[oi] += v;
            else out[oi] = v;
        }
    }
}

extern "C" void kernel_launch(void* const* d_in, const int* in_sizes, int n_in,
                              void* d_out, int out_size, void* d_ws, size_t ws_size,
                              hipStream_t stream) {
    const float* x1      = (const float*)d_in[0];
    const float* x2      = (const float*)d_in[1];
    const float* d1_w1   = (const float*)d_in[2];
    const float* d1_w2   = (const float*)d_in[3];
    const float* d2_w1   = (const float*)d_in[4];
    const float* d2_w2   = (const float*)d_in[5];
    const float* align_w = (const float*)d_in[6];
    const float* up_w1   = (const float*)d_in[7];
    const float* up_w2   = (const float*)d_in[8];
    const float* re_w1   = (const float*)d_in[9];
    const float* re_w2   = (const float*)d_in[10];
    float* out = (float*)d_out;
    float* ws  = (float*)d_ws;

    float* pooled = ws + OFF_POOLED;
    float* wk     = ws + OFF_WK;
    unsigned short* Wt   = (unsigned short*)(ws + OFF_WC);
    unsigned short* Wf   = (unsigned short*)(ws + OFF_WA);
    unsigned short* bufT = (unsigned short*)(ws + OFF_T);
    unsigned short* bufA = (unsigned short*)(ws + OFF_A);
    unsigned short* bufB = (unsigned short*)(ws + OFF_B);
    unsigned short* bufF = (unsigned short*)(ws + OFF_F);
    float* bufR1  = ws + OFF_T;  // reuse T region (dead by re1)

    wcomb_kernel<<<1152, 256, 0, stream>>>(up_w1, up_w2, Wt);
    awprep_kernel<<<1, 256, 0, stream>>>(align_w, Wf);

    for (int which = 0; which < 2; which++) {
        const float* x = which ? x2 : x1;
        unsigned short* dst = which ? bufB : bufA;
        pool_mean_kernel<<<2048, 256, 0, stream>>>(x, pooled);
        wk_kernel<<<16, 128, 0, stream>>>(pooled, d1_w1, d1_w2, wk);
        dsc_apply_kernel<float, unsigned short, true>
            <<<2048, 256, 0, stream>>>(x, wk, bufT, pooled);
        wk_kernel<<<16, 128, 0, stream>>>(pooled, d2_w1, d2_w2, wk);
        dsc_apply_kernel<unsigned short, unsigned short, false>
            <<<2048, 256, 0, stream>>>(bufT, wk, dst, nullptr);
    }

    align_mfma_kernel<<<dim3(32, 16), 256, 0, stream>>>(bufA, bufB, Wf, bufF);

    // up-conv (conv3x3 + pixel_shuffle + 1x1 fused) via bf16 MFMA implicit GEMM
    up_mfma_kernel<<<dim3(32, 16), 256, 0, stream>>>(bufF, Wt, out);

    // re1: conv3x3(up) -> relu -> [16,8,128,128]
    conv3x3_kernel<64, 8, 128, 128, 16, 8, 4, 64, 4, 2, true, false>
        <<<dim3(64, 1, 16), 256, 0, stream>>>(out, re_w1, bufR1);

    // re2: conv3x3 -> accumulate into out (out = up + re)
    conv3x3_kernel<8, 64, 128, 128, 8, 32, 4, 64, 8, 4, false, true>
        <<<dim3(64, 2, 16), 256, 0, stream>>>(bufR1, re_w2, out);
}

// Round 4
// 399.350 us; speedup vs baseline: 2.6508x; 1.2167x over previous
//
#include <hip/hip_runtime.h>
#include <math.h>

typedef unsigned short ushort;
typedef short bf16x8 __attribute__((ext_vector_type(8)));
typedef float f32x16 __attribute__((ext_vector_type(16)));
typedef float f32x4 __attribute__((ext_vector_type(4)));

// ---------------- workspace layout (float elements) ----------------
static const size_t OFF_POOLED = 0;         // 4096 f (2 inputs x 2048)
static const size_t OFF_WK     = 4096;      // 36864 f (2 x 16*128*9)
static const size_t OFF_WT     = 40960;     // Wt 294912 sh = 147456 f
static const size_t OFF_WF     = 188416;    // Wf 32768 sh = 16384 f
static const size_t OFF_AW1    = 204800;    // 9216 sh = 4608 f
static const size_t OFF_AW2    = 209408;    // 5120 sh = 2560 f
static const size_t OFF_T      = 262144;    // bufT 2x8M sh = 8388608 f ; R1 aliases
static const size_t OFF_AB     = 8650752;   // bufAB 2x8M sh = 8388608 f ; bufU aliases
static const size_t OFF_F      = 17039360;  // F 8388608 sh = 4194304 f
// total 21233664 f = 85 MB

static __device__ __forceinline__ ushort f2bf(float f) {
    unsigned int u = __builtin_bit_cast(unsigned int, f);
    u += 0x7FFF + ((u >> 16) & 1);
    return (ushort)(u >> 16);
}
static __device__ __forceinline__ float bf2f(ushort u) {
    return __builtin_bit_cast(float, ((unsigned int)u) << 16);
}

// ---------------- pooling (both inputs): pooled[bc] -------------------------
__global__ __launch_bounds__(256) void pool_both_kernel(const float* __restrict__ x1,
                                                        const float* __restrict__ x2,
                                                        float* __restrict__ pooled) {
    int bc = blockIdx.x;  // 4096
    const float* x = (bc >> 11) ? x2 : x1;
    const float4* p = (const float4*)(x + (size_t)(bc & 2047) * 4096);
    float s = 0.f;
    for (int i = threadIdx.x; i < 1024; i += 256) {
        float4 v = p[i];
        s += v.x + v.y + v.z + v.w;
    }
    #pragma unroll
    for (int off = 32; off; off >>= 1) s += __shfl_down(s, off);
    __shared__ float r4[4];
    if ((threadIdx.x & 63) == 0) r4[threadIdx.x >> 6] = s;
    __syncthreads();
    if (threadIdx.x == 0) pooled[bc] = (r4[0] + r4[1] + r4[2] + r4[3]) * (1.f / 4096.f);
}

// ------------- wk: gelu(pooled@w1^T)@w2^T -> softmax over 9 (grid 32) -------
__global__ __launch_bounds__(128) void wk_kernel(const float* __restrict__ pooled,
                                                 const float* __restrict__ w1,
                                                 const float* __restrict__ w2,
                                                 float* __restrict__ wk) {
    int b = blockIdx.x;
    __shared__ float sp[128];
    __shared__ float sh[16];
    int t = threadIdx.x;
    sp[t] = pooled[b * 128 + t];
    __syncthreads();
    if (t < 16) {
        float acc = 0.f;
        #pragma unroll 4
        for (int c = 0; c < 128; c++) acc += w1[t * 128 + c] * sp[c];
        sh[t] = 0.5f * acc * (1.f + erff(acc * 0.70710678118654752f));
    }
    __syncthreads();
    float lg[9];
    float m = -INFINITY;
    #pragma unroll
    for (int k = 0; k < 9; k++) {
        float acc = 0.f;
        const float* wr = w2 + (size_t)(t * 9 + k) * 16;
        #pragma unroll
        for (int r = 0; r < 16; r++) acc += wr[r] * sh[r];
        lg[k] = acc;
        m = fmaxf(m, acc);
    }
    float se = 0.f;
    #pragma unroll
    for (int k = 0; k < 9; k++) { lg[k] = expf(lg[k] - m); se += lg[k]; }
    float inv = 1.f / se;
    #pragma unroll
    for (int k = 0; k < 9; k++) wk[(size_t)(b * 128 + t) * 9 + k] = lg[k] * inv;
}

// -------- dsc1: f32 in, bf16 out, relu+pool (both inputs) -------------------
__global__ __launch_bounds__(256) void dsc1_kernel(const float* __restrict__ x1,
                                                   const float* __restrict__ x2,
                                                   const float* __restrict__ wk,
                                                   ushort* __restrict__ y,
                                                   float* __restrict__ pooled2) {
    int bc = blockIdx.x;  // 4096
    const float* xp = ((bc >> 11) ? x2 : x1) + (size_t)(bc & 2047) * 4096;
    ushort* yp = y + (size_t)bc * 4096;
    __shared__ float tile[66 * 66];
    __shared__ float r4[4];
    int t = threadIdx.x;
    for (int i = t; i < 66 * 66; i += 256) tile[i] = 0.f;
    __syncthreads();
    const float4* xp4 = (const float4*)xp;
    for (int i = t; i < 1024; i += 256) {
        float4 v = xp4[i];
        int h = i >> 4, w = (i & 15) * 4;
        float* d = &tile[(h + 1) * 66 + w + 1];
        d[0] = v.x; d[1] = v.y; d[2] = v.z; d[3] = v.w;
    }
    __syncthreads();
    float kk[9];
    #pragma unroll
    for (int k = 0; k < 9; k++) kk[k] = wk[(size_t)bc * 9 + k];
    float psum = 0.f;
    for (int i = t * 2; i < 4096; i += 512) {
        int h = i >> 6, w = i & 63;
        const float* c = &tile[h * 66 + w];
        float v0 = kk[0]*c[0] + kk[1]*c[1] + kk[2]*c[2]
                 + kk[3]*c[66] + kk[4]*c[67] + kk[5]*c[68]
                 + kk[6]*c[132] + kk[7]*c[133] + kk[8]*c[134] + c[67];
        float v1 = kk[0]*c[1] + kk[1]*c[2] + kk[2]*c[3]
                 + kk[3]*c[67] + kk[4]*c[68] + kk[5]*c[69]
                 + kk[6]*c[133] + kk[7]*c[134] + kk[8]*c[135] + c[68];
        v0 = fmaxf(v0, 0.f); v1 = fmaxf(v1, 0.f);
        psum += v0 + v1;
        ushort2 pk = {f2bf(v0), f2bf(v1)};
        *(ushort2*)&yp[i] = pk;
    }
    #pragma unroll
    for (int off = 32; off; off >>= 1) psum += __shfl_down(psum, off);
    if ((t & 63) == 0) r4[t >> 6] = psum;
    __syncthreads();
    if (t == 0) pooled2[bc] = (r4[0] + r4[1] + r4[2] + r4[3]) * (1.f / 4096.f);
}

// -------- dsc2: bf16 in, bf16 out (both inputs) -----------------------------
__global__ __launch_bounds__(256) void dsc2_kernel(const ushort* __restrict__ x,
                                                   const float* __restrict__ wk,
                                                   ushort* __restrict__ y) {
    int bc = blockIdx.x;  // 4096
    const ushort* xp = x + (size_t)bc * 4096;
    ushort* yp = y + (size_t)bc * 4096;
    __shared__ float tile[66 * 66];
    int t = threadIdx.x;
    for (int i = t; i < 66 * 66; i += 256) tile[i] = 0.f;
    __syncthreads();
    for (int i = t; i < 512; i += 256) {
        int4 raw = *(const int4*)&xp[i * 8];
        const ushort* u = (const ushort*)&raw;
        int h = i >> 3, w = (i & 7) * 8;
        float* d = &tile[(h + 1) * 66 + w + 1];
        #pragma unroll
        for (int j = 0; j < 8; j++) d[j] = bf2f(u[j]);
    }
    __syncthreads();
    float kk[9];
    #pragma unroll
    for (int k = 0; k < 9; k++) kk[k] = wk[(size_t)bc * 9 + k];
    for (int i = t * 2; i < 4096; i += 512) {
        int h = i >> 6, w = i & 63;
        const float* c = &tile[h * 66 + w];
        float v0 = kk[0]*c[0] + kk[1]*c[1] + kk[2]*c[2]
                 + kk[3]*c[66] + kk[4]*c[67] + kk[5]*c[68]
                 + kk[6]*c[132] + kk[7]*c[133] + kk[8]*c[134] + c[67];
        float v1 = kk[0]*c[1] + kk[1]*c[2] + kk[2]*c[3]
                 + kk[3]*c[67] + kk[4]*c[68] + kk[5]*c[69]
                 + kk[6]*c[133] + kk[7]*c[134] + kk[8]*c[135] + c[68];
        ushort2 pk = {f2bf(v0), f2bf(v1)};
        *(ushort2*)&yp[i] = pk;
    }
}

// ---- align weight prep: Wf [step(16)][mt(4)][lane(64)][8] ------------------
__global__ __launch_bounds__(256) void awprep_kernel(const float* __restrict__ W,
                                                     ushort* __restrict__ Wf) {
    int t = threadIdx.x;
    #pragma unroll 1
    for (int i = 0; i < 16; i++) {
        int tk = t + (i << 8);
        int step = tk >> 8, mt = (tk >> 6) & 3, lane = tk & 63;
        int o = mt * 32 + (lane & 31);
        int cb = step * 16 + (lane >> 5) * 8;
        #pragma unroll
        for (int j = 0; j < 8; j++) Wf[(size_t)tk * 8 + j] = f2bf(W[o * 256 + cb + j]);
    }
}

// ---- align: F[b][px][128c] = W @ concat(A,B), bf16 MFMA --------------------
__global__ __launch_bounds__(256, 2) void align_mfma_kernel(const ushort* __restrict__ A,
                                                            const ushort* __restrict__ Bv,
                                                            const ushort* __restrict__ Wf,
                                                            ushort* __restrict__ F) {
    __shared__ ushort Xs[2 * 128 * 8];
    const int b = blockIdx.y;
    const int px0 = blockIdx.x << 7;
    const int tid = threadIdx.x;
    const int wave = tid >> 6, lane = tid & 63;
    const int l31 = lane & 31, half = lane >> 5;

    f32x16 acc[4];
    #pragma unroll
    for (int mt = 0; mt < 4; mt++)
        #pragma unroll
        for (int r = 0; r < 16; r++) acc[mt][r] = 0.f;

    const int cg0 = tid >> 7, pxs0 = tid & 127;
    const int bfofs = (wave * 32 + l31) * 8 + half * 1024;

    for (int step = 0; step < 16; step++) {
        const ushort* src =
            (step < 8 ? A : Bv) + (((size_t)(b * 128 + (step & 7) * 16)) << 12) + px0;
        if (step) __syncthreads();
        #pragma unroll
        for (int q = 0; q < 2; q++) {
            int cg = cg0 + q * 2, px = pxs0;
            ushort v0 = src[((size_t)(cg * 4 + 0) << 12) + px];
            ushort v1 = src[((size_t)(cg * 4 + 1) << 12) + px];
            ushort v2 = src[((size_t)(cg * 4 + 2) << 12) + px];
            ushort v3 = src[((size_t)(cg * 4 + 3) << 12) + px];
            ushort4 pk = {v0, v1, v2, v3};
            *(ushort4*)&Xs[(cg >> 1) * 1024 + px * 8 + (cg & 1) * 4] = pk;
        }
        __syncthreads();
        bf16x8 bfrag = *(const bf16x8*)&Xs[bfofs];
        const bf16x8* wf = (const bf16x8*)(Wf + ((size_t)step * 4 * 64 + lane) * 8);
        #pragma unroll
        for (int mt = 0; mt < 4; mt++)
            acc[mt] = __builtin_amdgcn_mfma_f32_32x32x16_bf16(wf[mt * 64], bfrag, acc[mt], 0, 0, 0);
    }
    // epilogue: F[b][px][c]; o = mt*32 + half*4 + 8*g + i
    ushort* fp = F + ((size_t)(b * 4096 + px0 + wave * 32 + l31)) * 128;
    #pragma unroll
    for (int mt = 0; mt < 4; mt++) {
        #pragma unroll
        for (int g = 0; g < 4; g++) {
            ushort4 pk = {f2bf(acc[mt][g * 4 + 0]), f2bf(acc[mt][g * 4 + 1]),
                          f2bf(acc[mt][g * 4 + 2]), f2bf(acc[mt][g * 4 + 3])};
            *(ushort4*)(fp + mt * 32 + half * 4 + 8 * g) = pk;
        }
    }
}

// ---- combined up weight, bf16: Wt[tap][op][cin] ----------------------------
__global__ __launch_bounds__(256) void wcomb_kernel(const float* __restrict__ w1,
                                                    const float* __restrict__ w2,
                                                    ushort* __restrict__ Wt) {
    int idx = blockIdx.x * 256 + threadIdx.x;  // < 294912
    int cin = idx & 127;
    int op = (idx >> 7) & 255;
    int tap = idx >> 15;
    int o = op >> 2, ph = op & 3;
    float acc = 0.f;
    #pragma unroll 4
    for (int c = 0; c < 128; c++)
        acc += w2[o * 128 + c] * w1[((size_t)(c * 4 + ph) * 128 + cin) * 9 + tap];
    Wt[idx] = f2bf(acc);
}

// ---- re1 weight prep: Aw1[s(18)][lane(64)][8]  (16x16x32 A-frag order) -----
__global__ __launch_bounds__(256) void aw1prep_kernel(const float* __restrict__ w1,  // [8,64,3,3]
                                                      ushort* __restrict__ Aw1) {
    int idx = blockIdx.x * 256 + threadIdx.x;  // < 9216
    if (idx >= 9216) return;
    int j = idx & 7, lane = (idx >> 3) & 63, s = idx >> 9;
    int m = lane & 15, kq = lane >> 4;
    int tap = s >> 1, ch = s & 1;
    int cin = ch * 32 + kq * 8 + j;
    float v = (m < 8) ? w1[((size_t)(m * 64 + cin)) * 9 + tap] : 0.f;
    Aw1[idx] = f2bf(v);
}

// ---- re2 weight prep: Aw2[s(5)][mt(2)][lane(64)][8] (32x32x16 A-frag) ------
__global__ __launch_bounds__(256) void aw2prep_kernel(const float* __restrict__ w2,  // [64,8,3,3]
                                                      ushort* __restrict__ Aw2) {
    int idx = blockIdx.x * 256 + threadIdx.x;  // < 5120
    if (idx >= 5120) return;
    int j = idx & 7, lane = (idx >> 3) & 63, mt = (idx >> 9) & 1, s = idx >> 10;
    int m = mt * 32 + (lane & 31), half = lane >> 5;
    int k = s * 16 + half * 8 + j;
    int tap = k >> 3, c = k & 7;
    float v = (tap < 9) ? w2[((size_t)(m * 8 + c)) * 9 + tap] : 0.f;
    Aw2[idx] = f2bf(v);
}

// ------ up-conv: implicit GEMM 32x32x16 bf16, F[b,px,c] -> U[b,Y,X,64] ------
// Block: 256 op x 128 px (16h x 8w). Waves: mh=wave>>1 (op half), nh=wave&1 (px half).
__global__ __launch_bounds__(256, 2) void up_mfma_kernel(const ushort* __restrict__ F,
                                                         const ushort* __restrict__ Wt,
                                                         ushort* __restrict__ U) {
    __shared__ ushort Xs[180 * 136];  // 48960 B; epilogue reuses as [256px][68]
    const int b = blockIdx.y;
    const int tr = blockIdx.x >> 3, tc = blockIdx.x & 7;
    const int tid = threadIdx.x;
    const int wave = tid >> 6, lane = tid & 63;
    const int l31 = lane & 31, half = lane >> 5;
    const int mh = wave >> 1, nh = wave & 1;

    // stage whole 18x10 halo x 128c, coalesced 16B, conflict-free (136 sh stride)
    for (int idx = tid; idx < 2880; idx += 256) {
        int px = idx >> 4, q = idx & 15;
        int r = px / 10, c = px - r * 10;
        int gh = tr * 16 - 1 + r, gw = tc * 8 - 1 + c;
        int4 v = {0, 0, 0, 0};
        if ((unsigned)gh < 64u && (unsigned)gw < 64u)
            v = *(const int4*)(F + ((size_t)(b * 4096 + gh * 64 + gw)) * 128 + q * 8);
        *(int4*)&Xs[px * 136 + q * 8] = v;
    }
    __syncthreads();

    f32x16 acc[4][2];
    #pragma unroll
    for (int mt = 0; mt < 4; mt++)
        #pragma unroll
        for (int nt = 0; nt < 2; nt++)
            #pragma unroll
            for (int r = 0; r < 16; r++) acc[mt][nt][r] = 0.f;

    const ushort* ap[4];
    #pragma unroll
    for (int mt = 0; mt < 4; mt++)
        ap[mt] = Wt + (size_t)(mh * 128 + mt * 32 + l31) * 128 + half * 8;
    int xb[2];
    #pragma unroll
    for (int nt = 0; nt < 2; nt++) {
        int pxl = nh * 64 + nt * 32 + l31;
        xb[nt] = ((pxl >> 3) * 10 + (pxl & 7)) * 136 + half * 8;
    }

    bf16x8 aC[4], aN[4];
    #pragma unroll
    for (int mt = 0; mt < 4; mt++) aC[mt] = *(const bf16x8*)(ap[mt]);  // s=0

    #pragma unroll 1
    for (int s = 0; s < 72; s++) {
        int tap = s >> 3, c16 = s & 7;
        if (s < 71) {
            int t2 = (s + 1) >> 3, c2 = (s + 1) & 7;
            #pragma unroll
            for (int mt = 0; mt < 4; mt++)
                aN[mt] = *(const bf16x8*)(ap[mt] + t2 * 32768 + c2 * 16);
        }
        int ky = tap / 3, kx = tap - ky * 3;
        int xoff = (ky * 10 + kx) * 136 + c16 * 16;
        bf16x8 b0 = *(const bf16x8*)&Xs[xb[0] + xoff];
        bf16x8 b1 = *(const bf16x8*)&Xs[xb[1] + xoff];
        #pragma unroll
        for (int mt = 0; mt < 4; mt++) {
            acc[mt][0] = __builtin_amdgcn_mfma_f32_32x32x16_bf16(aC[mt], b0, acc[mt][0], 0, 0, 0);
            acc[mt][1] = __builtin_amdgcn_mfma_f32_32x32x16_bf16(aC[mt], b1, acc[mt][1], 0, 0, 0);
        }
        #pragma unroll
        for (int mt = 0; mt < 4; mt++) aC[mt] = aN[mt];
    }

    // epilogue: shuffle via LDS, two passes of 16x16 shuffled px x 64 ch
    const int S2 = 68;
    #pragma unroll 1
    for (int p = 0; p < 2; p++) {
        __syncthreads();
        if (nh == p) {
            #pragma unroll
            for (int nt = 0; nt < 2; nt++) {
                int pxl = nh * 64 + nt * 32 + l31;
                int rowl = pxl >> 3, coll = pxl & 7;
                int Y0 = 2 * (rowl - 8 * p), X0 = 2 * coll;
                #pragma unroll
                for (int mt = 0; mt < 4; mt++) {
                    #pragma unroll
                    for (int g = 0; g < 4; g++) {
                        int o = mh * 32 + mt * 8 + 2 * g + half;
                        #pragma unroll
                        for (int i = 0; i < 4; i++) {
                            int ry = (i >> 1), rx = i & 1;
                            Xs[((Y0 + ry) * 16 + X0 + rx) * S2 + o] =
                                f2bf(acc[mt][nt][g * 4 + i]);
                        }
                    }
                }
            }
        }
        __syncthreads();
        for (int idx = tid; idx < 4096; idx += 256) {
            int px = idx >> 4, q = idx & 15;
            ushort4 v = *(ushort4*)&Xs[px * S2 + q * 4];
            int Yg = tr * 32 + p * 16 + (px >> 4), Xg = tc * 16 + (px & 15);
            *(ushort4*)(U + ((size_t)((b * 128 + Yg) * 128 + Xg)) * 64 + q * 4) = v;
        }
    }
}

// ------ re1: conv3x3(U,re_w1)+relu via 16x16x32 MFMA -> R1[b,Y,X,8] ---------
__global__ __launch_bounds__(256, 2) void re1_kernel(const ushort* __restrict__ U,
                                                     const ushort* __restrict__ Aw1,
                                                     ushort* __restrict__ R1) {
    __shared__ ushort Xs[324 * 72];  // 46656 B
    __shared__ ushort As[18 * 64 * 8];
    const int b = blockIdx.y;
    const int ty = blockIdx.x >> 3, tx = blockIdx.x & 7;
    const int tid = threadIdx.x;
    const int wave = tid >> 6, lane = tid & 63;
    const int m16 = lane & 15, kq = lane >> 4;

    for (int idx = tid; idx < 1152; idx += 256)
        *(int4*)&As[idx * 8] = *(const int4*)(Aw1 + (size_t)idx * 8);
    for (int idx = tid; idx < 2592; idx += 256) {
        int px = idx >> 3, q = idx & 7;
        int r = px / 18, c = px - r * 18;
        int gY = ty * 16 - 1 + r, gX = tx * 16 - 1 + c;
        int4 v = {0, 0, 0, 0};
        if ((unsigned)gY < 128u && (unsigned)gX < 128u)
            v = *(const int4*)(U + ((size_t)((b * 128 + gY) * 128 + gX)) * 64 + q * 8);
        *(int4*)&Xs[px * 72 + q * 8] = v;
    }
    __syncthreads();

    f32x4 acc[4];
    #pragma unroll
    for (int nt = 0; nt < 4; nt++)
        #pragma unroll
        for (int r = 0; r < 4; r++) acc[nt][r] = 0.f;

    #pragma unroll 1
    for (int s = 0; s < 18; s++) {
        bf16x8 a = *(const bf16x8*)&As[(s * 64 + lane) * 8];
        int tap = s >> 1, ch = s & 1;
        int ky = tap / 3, kx = tap - ky * 3;
        int xo = (ky * 18 + kx) * 72 + ch * 32 + kq * 8;
        #pragma unroll
        for (int nt = 0; nt < 4; nt++) {
            int row = wave * 4 + nt;
            bf16x8 bv = *(const bf16x8*)&Xs[(row * 18 + m16) * 72 + xo];
            acc[nt] = __builtin_amdgcn_mfma_f32_16x16x32_bf16(a, bv, acc[nt], 0, 0, 0);
        }
    }
    if (kq < 2) {
        #pragma unroll
        for (int nt = 0; nt < 4; nt++) {
            int gY = ty * 16 + wave * 4 + nt, gX = tx * 16 + m16;
            ushort4 pk = {f2bf(fmaxf(acc[nt][0], 0.f)), f2bf(fmaxf(acc[nt][1], 0.f)),
                          f2bf(fmaxf(acc[nt][2], 0.f)), f2bf(fmaxf(acc[nt][3], 0.f))};
            *(ushort4*)(R1 + ((size_t)((b * 128 + gY) * 128 + gX)) * 8 + kq * 4) = pk;
        }
    }
}

// ------ re2: conv3x3(R1,re_w2) + up  via 32x32x16 MFMA -> out f32 planar ----
__global__ __launch_bounds__(256, 2) void re2_kernel(const ushort* __restrict__ R1,
                                                     const ushort* __restrict__ U,
                                                     const ushort* __restrict__ Aw2,
                                                     float* __restrict__ out) {
    __shared__ ushort Xs[324 * 8];   // 5184 B
    __shared__ ushort As[5 * 2 * 64 * 8];
    __shared__ ushort Us[256 * 68];  // 34816 B
    const int b = blockIdx.y;
    const int ty = blockIdx.x >> 3, tx = blockIdx.x & 7;
    const int tid = threadIdx.x;
    const int wave = tid >> 6, lane = tid & 63;
    const int l31 = lane & 31, half = lane >> 5;

    for (int idx = tid; idx < 640; idx += 256)
        *(int4*)&As[idx * 8] = *(const int4*)(Aw2 + (size_t)idx * 8);
    for (int idx = tid; idx < 324; idx += 256) {
        int r = idx / 18, c = idx - r * 18;
        int gY = ty * 16 - 1 + r, gX = tx * 16 - 1 + c;
        int4 v = {0, 0, 0, 0};
        if ((unsigned)gY < 128u && (unsigned)gX < 128u)
            v = *(const int4*)(R1 + ((size_t)((b * 128 + gY) * 128 + gX)) * 8);
        *(int4*)&Xs[idx * 8] = v;
    }
    for (int idx = tid; idx < 2048; idx += 256) {
        int px = idx >> 3, q = idx & 7;
        int gY = ty * 16 + (px >> 4), gX = tx * 16 + (px & 15);
        const ushort* s = U + ((size_t)((b * 128 + gY) * 128 + gX)) * 64 + q * 8;
        ushort4 v0 = *(const ushort4*)s;
        ushort4 v1 = *(const ushort4*)(s + 4);
        *(ushort4*)&Us[px * 68 + q * 8] = v0;
        *(ushort4*)&Us[px * 68 + q * 8 + 4] = v1;
    }
    __syncthreads();

    f32x16 acc[2][2];
    #pragma unroll
    for (int mt = 0; mt < 2; mt++)
        #pragma unroll
        for (int nt = 0; nt < 2; nt++)
            #pragma unroll
            for (int r = 0; r < 16; r++) acc[mt][nt][r] = 0.f;

    #pragma unroll
    for (int s = 0; s < 5; s++) {
        bf16x8 a0 = *(const bf16x8*)&As[((s * 2 + 0) * 64 + lane) * 8];
        bf16x8 a1 = *(const bf16x8*)&As[((s * 2 + 1) * 64 + lane) * 8];
        int t = 2 * s + half;
        if (t > 8) t = 8;  // A is zero there
        int ky = t / 3, kx = t - ky * 3;
        #pragma unroll
        for (int nt = 0; nt < 2; nt++) {
            int pxl = wave * 64 + nt * 32 + l31;
            int row = pxl >> 4, col = pxl & 15;
            bf16x8 bv = *(const bf16x8*)&Xs[((row + ky) * 18 + col + kx) * 8];
            acc[0][nt] = __builtin_amdgcn_mfma_f32_32x32x16_bf16(a0, bv, acc[0][nt], 0, 0, 0);
            acc[1][nt] = __builtin_amdgcn_mfma_f32_32x32x16_bf16(a1, bv, acc[1][nt], 0, 0, 0);
        }
    }
    #pragma unroll
    for (int mt = 0; mt < 2; mt++) {
        #pragma unroll
        for (int nt = 0; nt < 2; nt++) {
            int pxl = wave * 64 + nt * 32 + l31;
            int gY = ty * 16 + (pxl >> 4), gX = tx * 16 + (pxl & 15);
            #pragma unroll
            for (int r = 0; r < 16; r++) {
                int o = mt * 32 + (r & 3) + 8 * (r >> 2) + 4 * half;
                float v = acc[mt][nt][r] + bf2f(Us[pxl * 68 + o]);
                out[((size_t)(b * 64 + o) * 128 + gY) * 128 + gX] = v;
            }
        }
    }
}

extern "C" void kernel_launch(void* const* d_in, const int* in_sizes, int n_in,
                              void* d_out, int out_size, void* d_ws, size_t ws_size,
                              hipStream_t stream) {
    const float* x1      = (const float*)d_in[0];
    const float* x2      = (const float*)d_in[1];
    const float* d1_w1   = (const float*)d_in[2];
    const float* d1_w2   = (const float*)d_in[3];
    const float* d2_w1   = (const float*)d_in[4];
    const float* d2_w2   = (const float*)d_in[5];
    const float* align_w = (const float*)d_in[6];
    const float* up_w1   = (const float*)d_in[7];
    const float* up_w2   = (const float*)d_in[8];
    const float* re_w1   = (const float*)d_in[9];
    const float* re_w2   = (const float*)d_in[10];
    float* out = (float*)d_out;
    float* ws  = (float*)d_ws;

    float*  pooled = ws + OFF_POOLED;
    float*  wkb    = ws + OFF_WK;
    ushort* Wt     = (ushort*)(ws + OFF_WT);
    ushort* Wf     = (ushort*)(ws + OFF_WF);
    ushort* Aw1    = (ushort*)(ws + OFF_AW1);
    ushort* Aw2    = (ushort*)(ws + OFF_AW2);
    ushort* bufT   = (ushort*)(ws + OFF_T);
    ushort* R1     = (ushort*)(ws + OFF_T);   // alias (bufT dead by re1)
    ushort* bufAB  = (ushort*)(ws + OFF_AB);
    ushort* bufU   = (ushort*)(ws + OFF_AB);  // alias (bufAB dead after align)
    ushort* F      = (ushort*)(ws + OFF_F);

    wcomb_kernel<<<1152, 256, 0, stream>>>(up_w1, up_w2, Wt);
    awprep_kernel<<<1, 256, 0, stream>>>(align_w, Wf);
    aw1prep_kernel<<<36, 256, 0, stream>>>(re_w1, Aw1);
    aw2prep_kernel<<<20, 256, 0, stream>>>(re_w2, Aw2);

    pool_both_kernel<<<4096, 256, 0, stream>>>(x1, x2, pooled);
    wk_kernel<<<32, 128, 0, stream>>>(pooled, d1_w1, d1_w2, wkb);
    dsc1_kernel<<<4096, 256, 0, stream>>>(x1, x2, wkb, bufT, pooled);
    wk_kernel<<<32, 128, 0, stream>>>(pooled, d2_w1, d2_w2, wkb);
    dsc2_kernel<<<4096, 256, 0, stream>>>(bufT, wkb, bufAB);

    align_mfma_kernel<<<dim3(32, 16), 256, 0, stream>>>(bufAB, bufAB + 8388608, Wf, F);
    up_mfma_kernel<<<dim3(32, 16), 256, 0, stream>>>(F, Wt, bufU);
    re1_kernel<<<dim3(64, 16), 256, 0, stream>>>(bufU, Aw1, R1);
    re2_kernel<<<dim3(64, 16), 256, 0, stream>>>(R1, bufU, Aw2, out);
}

// Round 5
// 361.463 us; speedup vs baseline: 2.9287x; 1.1048x over previous
//
#include <hip/hip_runtime.h>
#include <math.h>

typedef unsigned short ushort;
typedef short bf16x8 __attribute__((ext_vector_type(8)));
typedef float f32x16 __attribute__((ext_vector_type(16)));
typedef float f32x4 __attribute__((ext_vector_type(4)));

// ---------------- workspace layout (float elements) ----------------
static const size_t OFF_POOLED = 0;         // 4096 f (2 inputs x 2048)
static const size_t OFF_WK     = 4096;      // 36864 f (2 x 16*128*9)
static const size_t OFF_WT     = 40960;     // Awt 294912 sh = 147456 f
static const size_t OFF_WF     = 188416;    // Wf 32768 sh = 16384 f
static const size_t OFF_AW1    = 204800;    // 9216 sh = 4608 f
static const size_t OFF_AW2    = 209408;    // 5120 sh = 2560 f
static const size_t OFF_T      = 262144;    // bufT 2x8M sh = 8388608 f ; R1 aliases
static const size_t OFF_AB     = 8650752;   // bufAB 2x8M sh = 8388608 f ; bufU aliases
static const size_t OFF_F      = 17039360;  // F 8388608 sh = 4194304 f
// total 21233664 f = 85 MB

static __device__ __forceinline__ ushort f2bf(float f) {
    unsigned int u = __builtin_bit_cast(unsigned int, f);
    u += 0x7FFF + ((u >> 16) & 1);
    return (ushort)(u >> 16);
}
static __device__ __forceinline__ float bf2f(ushort u) {
    return __builtin_bit_cast(float, ((unsigned int)u) << 16);
}

// ---------------- pooling (both inputs): pooled[bc] -------------------------
__global__ __launch_bounds__(256) void pool_both_kernel(const float* __restrict__ x1,
                                                        const float* __restrict__ x2,
                                                        float* __restrict__ pooled) {
    int bc = blockIdx.x;  // 4096
    const float* x = (bc >> 11) ? x2 : x1;
    const float4* p = (const float4*)(x + (size_t)(bc & 2047) * 4096);
    float s = 0.f;
    for (int i = threadIdx.x; i < 1024; i += 256) {
        float4 v = p[i];
        s += v.x + v.y + v.z + v.w;
    }
    #pragma unroll
    for (int off = 32; off; off >>= 1) s += __shfl_down(s, off);
    __shared__ float r4[4];
    if ((threadIdx.x & 63) == 0) r4[threadIdx.x >> 6] = s;
    __syncthreads();
    if (threadIdx.x == 0) pooled[bc] = (r4[0] + r4[1] + r4[2] + r4[3]) * (1.f / 4096.f);
}

// ------------- wk: gelu(pooled@w1^T)@w2^T -> softmax over 9 (grid 32) -------
__global__ __launch_bounds__(128) void wk_kernel(const float* __restrict__ pooled,
                                                 const float* __restrict__ w1,
                                                 const float* __restrict__ w2,
                                                 float* __restrict__ wk) {
    int b = blockIdx.x;
    __shared__ float sp[128];
    __shared__ float sh[16];
    int t = threadIdx.x;
    sp[t] = pooled[b * 128 + t];
    __syncthreads();
    if (t < 16) {
        float acc = 0.f;
        #pragma unroll 4
        for (int c = 0; c < 128; c++) acc += w1[t * 128 + c] * sp[c];
        sh[t] = 0.5f * acc * (1.f + erff(acc * 0.70710678118654752f));
    }
    __syncthreads();
    float lg[9];
    float m = -INFINITY;
    #pragma unroll
    for (int k = 0; k < 9; k++) {
        float acc = 0.f;
        const float* wr = w2 + (size_t)(t * 9 + k) * 16;
        #pragma unroll
        for (int r = 0; r < 16; r++) acc += wr[r] * sh[r];
        lg[k] = acc;
        m = fmaxf(m, acc);
    }
    float se = 0.f;
    #pragma unroll
    for (int k = 0; k < 9; k++) { lg[k] = expf(lg[k] - m); se += lg[k]; }
    float inv = 1.f / se;
    #pragma unroll
    for (int k = 0; k < 9; k++) wk[(size_t)(b * 128 + t) * 9 + k] = lg[k] * inv;
}

// -------- dsc1: f32 in, bf16 out, relu+pool (both inputs) -------------------
__global__ __launch_bounds__(256) void dsc1_kernel(const float* __restrict__ x1,
                                                   const float* __restrict__ x2,
                                                   const float* __restrict__ wk,
                                                   ushort* __restrict__ y,
                                                   float* __restrict__ pooled2) {
    int bc = blockIdx.x;  // 4096
    const float* xp = ((bc >> 11) ? x2 : x1) + (size_t)(bc & 2047) * 4096;
    ushort* yp = y + (size_t)bc * 4096;
    __shared__ float tile[66 * 66];
    __shared__ float r4[4];
    int t = threadIdx.x;
    for (int i = t; i < 66 * 66; i += 256) tile[i] = 0.f;
    __syncthreads();
    const float4* xp4 = (const float4*)xp;
    for (int i = t; i < 1024; i += 256) {
        float4 v = xp4[i];
        int h = i >> 4, w = (i & 15) * 4;
        float* d = &tile[(h + 1) * 66 + w + 1];
        d[0] = v.x; d[1] = v.y; d[2] = v.z; d[3] = v.w;
    }
    __syncthreads();
    float kk[9];
    #pragma unroll
    for (int k = 0; k < 9; k++) kk[k] = wk[(size_t)bc * 9 + k];
    float psum = 0.f;
    for (int i = t * 2; i < 4096; i += 512) {
        int h = i >> 6, w = i & 63;
        const float* c = &tile[h * 66 + w];
        float v0 = kk[0]*c[0] + kk[1]*c[1] + kk[2]*c[2]
                 + kk[3]*c[66] + kk[4]*c[67] + kk[5]*c[68]
                 + kk[6]*c[132] + kk[7]*c[133] + kk[8]*c[134] + c[67];
        float v1 = kk[0]*c[1] + kk[1]*c[2] + kk[2]*c[3]
                 + kk[3]*c[67] + kk[4]*c[68] + kk[5]*c[69]
                 + kk[6]*c[133] + kk[7]*c[134] + kk[8]*c[135] + c[68];
        v0 = fmaxf(v0, 0.f); v1 = fmaxf(v1, 0.f);
        psum += v0 + v1;
        ushort2 pk = {f2bf(v0), f2bf(v1)};
        *(ushort2*)&yp[i] = pk;
    }
    #pragma unroll
    for (int off = 32; off; off >>= 1) psum += __shfl_down(psum, off);
    if ((t & 63) == 0) r4[t >> 6] = psum;
    __syncthreads();
    if (t == 0) pooled2[bc] = (r4[0] + r4[1] + r4[2] + r4[3]) * (1.f / 4096.f);
}

// -------- dsc2: bf16 in, bf16 out (both inputs) -----------------------------
__global__ __launch_bounds__(256) void dsc2_kernel(const ushort* __restrict__ x,
                                                   const float* __restrict__ wk,
                                                   ushort* __restrict__ y) {
    int bc = blockIdx.x;  // 4096
    const ushort* xp = x + (size_t)bc * 4096;
    ushort* yp = y + (size_t)bc * 4096;
    __shared__ float tile[66 * 66];
    int t = threadIdx.x;
    for (int i = t; i < 66 * 66; i += 256) tile[i] = 0.f;
    __syncthreads();
    for (int i = t; i < 512; i += 256) {
        int4 raw = *(const int4*)&xp[i * 8];
        const ushort* u = (const ushort*)&raw;
        int h = i >> 3, w = (i & 7) * 8;
        float* d = &tile[(h + 1) * 66 + w + 1];
        #pragma unroll
        for (int j = 0; j < 8; j++) d[j] = bf2f(u[j]);
    }
    __syncthreads();
    float kk[9];
    #pragma unroll
    for (int k = 0; k < 9; k++) kk[k] = wk[(size_t)bc * 9 + k];
    for (int i = t * 2; i < 4096; i += 512) {
        int h = i >> 6, w = i & 63;
        const float* c = &tile[h * 66 + w];
        float v0 = kk[0]*c[0] + kk[1]*c[1] + kk[2]*c[2]
                 + kk[3]*c[66] + kk[4]*c[67] + kk[5]*c[68]
                 + kk[6]*c[132] + kk[7]*c[133] + kk[8]*c[134] + c[67];
        float v1 = kk[0]*c[1] + kk[1]*c[2] + kk[2]*c[3]
                 + kk[3]*c[67] + kk[4]*c[68] + kk[5]*c[69]
                 + kk[6]*c[133] + kk[7]*c[134] + kk[8]*c[135] + c[68];
        ushort2 pk = {f2bf(v0), f2bf(v1)};
        *(ushort2*)&yp[i] = pk;
    }
}

// ---- align weight prep: Wf [step(16)][mt(4)][lane(64)][8] ------------------
__global__ __launch_bounds__(256) void awprep_kernel(const float* __restrict__ W,
                                                     ushort* __restrict__ Wf) {
    int t = threadIdx.x;
    #pragma unroll 1
    for (int i = 0; i < 16; i++) {
        int tk = t + (i << 8);
        int step = tk >> 8, mt = (tk >> 6) & 3, lane = tk & 63;
        int o = mt * 32 + (lane & 31);
        int cb = step * 16 + (lane >> 5) * 8;
        #pragma unroll
        for (int j = 0; j < 8; j++) Wf[(size_t)tk * 8 + j] = f2bf(W[o * 256 + cb + j]);
    }
}

// ---- align: F[b][px][128c] = W @ concat(A,B), bf16 MFMA --------------------
__global__ __launch_bounds__(256, 2) void align_mfma_kernel(const ushort* __restrict__ A,
                                                            const ushort* __restrict__ Bv,
                                                            const ushort* __restrict__ Wf,
                                                            ushort* __restrict__ F) {
    __shared__ ushort Xs[2 * 128 * 8];
    const int b = blockIdx.y;
    const int px0 = blockIdx.x << 7;
    const int tid = threadIdx.x;
    const int wave = tid >> 6, lane = tid & 63;
    const int l31 = lane & 31, half = lane >> 5;

    f32x16 acc[4];
    #pragma unroll
    for (int mt = 0; mt < 4; mt++)
        #pragma unroll
        for (int r = 0; r < 16; r++) acc[mt][r] = 0.f;

    const int cg0 = tid >> 7, pxs0 = tid & 127;
    const int bfofs = (wave * 32 + l31) * 8 + half * 1024;

    for (int step = 0; step < 16; step++) {
        const ushort* src =
            (step < 8 ? A : Bv) + (((size_t)(b * 128 + (step & 7) * 16)) << 12) + px0;
        if (step) __syncthreads();
        #pragma unroll
        for (int q = 0; q < 2; q++) {
            int cg = cg0 + q * 2, px = pxs0;
            ushort v0 = src[((size_t)(cg * 4 + 0) << 12) + px];
            ushort v1 = src[((size_t)(cg * 4 + 1) << 12) + px];
            ushort v2 = src[((size_t)(cg * 4 + 2) << 12) + px];
            ushort v3 = src[((size_t)(cg * 4 + 3) << 12) + px];
            ushort4 pk = {v0, v1, v2, v3};
            *(ushort4*)&Xs[(cg >> 1) * 1024 + px * 8 + (cg & 1) * 4] = pk;
        }
        __syncthreads();
        bf16x8 bfrag = *(const bf16x8*)&Xs[bfofs];
        const bf16x8* wf = (const bf16x8*)(Wf + ((size_t)step * 4 * 64 + lane) * 8);
        #pragma unroll
        for (int mt = 0; mt < 4; mt++)
            acc[mt] = __builtin_amdgcn_mfma_f32_32x32x16_bf16(wf[mt * 64], bfrag, acc[mt], 0, 0, 0);
    }
    // epilogue: F[b][px][c]; o = mt*32 + half*4 + 8*g + i
    ushort* fp = F + ((size_t)(b * 4096 + px0 + wave * 32 + l31)) * 128;
    #pragma unroll
    for (int mt = 0; mt < 4; mt++) {
        #pragma unroll
        for (int g = 0; g < 4; g++) {
            ushort4 pk = {f2bf(acc[mt][g * 4 + 0]), f2bf(acc[mt][g * 4 + 1]),
                          f2bf(acc[mt][g * 4 + 2]), f2bf(acc[mt][g * 4 + 3])};
            *(ushort4*)(fp + mt * 32 + half * 4 + 8 * g) = pk;
        }
    }
}

// ---- combined up weight in A-frag order: Awt[s=tap*8+c16][mh][mt][lane][8] -
// element: op = mh*128+mt*32+(lane&31), cin = c16*16+(lane>>5)*8+j
__global__ __launch_bounds__(256) void wcomb_kernel(const float* __restrict__ w1,
                                                    const float* __restrict__ w2,
                                                    ushort* __restrict__ Awt) {
    int idx = blockIdx.x * 256 + threadIdx.x;  // < 294912
    int j = idx & 7;
    int lane = (idx >> 3) & 63;
    int mt = (idx >> 9) & 3;
    int mh = (idx >> 11) & 1;
    int s = idx >> 12;             // 0..71
    int tap = s >> 3, c16 = s & 7;
    int op = mh * 128 + mt * 32 + (lane & 31);
    int cin = c16 * 16 + (lane >> 5) * 8 + j;
    int o = op >> 2, ph = op & 3;
    float acc = 0.f;
    #pragma unroll 4
    for (int c = 0; c < 128; c++)
        acc += w2[o * 128 + c] * w1[((size_t)(c * 4 + ph) * 128 + cin) * 9 + tap];
    Awt[idx] = f2bf(acc);
}

// ---- re1 weight prep: Aw1[s(18)][lane(64)][8]  (16x16x32 A-frag order) -----
__global__ __launch_bounds__(256) void aw1prep_kernel(const float* __restrict__ w1,  // [8,64,3,3]
                                                      ushort* __restrict__ Aw1) {
    int idx = blockIdx.x * 256 + threadIdx.x;  // < 9216
    if (idx >= 9216) return;
    int j = idx & 7, lane = (idx >> 3) & 63, s = idx >> 9;
    int m = lane & 15, kq = lane >> 4;
    int tap = s >> 1, ch = s & 1;
    int cin = ch * 32 + kq * 8 + j;
    float v = (m < 8) ? w1[((size_t)(m * 64 + cin)) * 9 + tap] : 0.f;
    Aw1[idx] = f2bf(v);
}

// ---- re2 weight prep: Aw2[s(5)][mt(2)][lane(64)][8] (32x32x16 A-frag) ------
__global__ __launch_bounds__(256) void aw2prep_kernel(const float* __restrict__ w2,  // [64,8,3,3]
                                                      ushort* __restrict__ Aw2) {
    int idx = blockIdx.x * 256 + threadIdx.x;  // < 5120
    if (idx >= 5120) return;
    int j = idx & 7, lane = (idx >> 3) & 63, mt = (idx >> 9) & 1, s = idx >> 10;
    int m = mt * 32 + (lane & 31), half = lane >> 5;
    int k = s * 16 + half * 8 + j;
    int tap = k >> 3, c = k & 7;
    float v = (tap < 9) ? w2[((size_t)(m * 8 + c)) * 9 + tap] : 0.f;
    Aw2[idx] = f2bf(v);
}

// ------ up-conv: implicit GEMM 32x32x16 bf16, F[b,px,c] -> U[b,Y,X,64] ------
// Block: 256 op x 128 px (16h x 8w). Waves: mh=wave>>1 (op half), nh=wave&1 (px half).
// A streamed from global in packed frag order with depth-2 register pipeline.
__global__ __launch_bounds__(256, 2) void up_mfma_kernel(const ushort* __restrict__ F,
                                                         const ushort* __restrict__ Awt,
                                                         ushort* __restrict__ U) {
    __shared__ ushort Xs[180 * 136];  // 48960 B; epilogue reuses as [256px][68]
    const int b = blockIdx.y;
    const int tr = blockIdx.x >> 3, tc = blockIdx.x & 7;
    const int tid = threadIdx.x;
    const int wave = tid >> 6, lane = tid & 63;
    const int l31 = lane & 31, half = lane >> 5;
    const int mh = wave >> 1, nh = wave & 1;

    // stage whole 18x10 halo x 128c, coalesced 16B (136 sh stride)
    for (int idx = tid; idx < 2880; idx += 256) {
        int px = idx >> 4, q = idx & 15;
        int r = px / 10, c = px - r * 10;
        int gh = tr * 16 - 1 + r, gw = tc * 8 - 1 + c;
        int4 v = {0, 0, 0, 0};
        if ((unsigned)gh < 64u && (unsigned)gw < 64u)
            v = *(const int4*)(F + ((size_t)(b * 4096 + gh * 64 + gw)) * 128 + q * 8);
        *(int4*)&Xs[px * 136 + q * 8] = v;
    }
    __syncthreads();

    f32x16 acc[4][2];
    #pragma unroll
    for (int mt = 0; mt < 4; mt++)
        #pragma unroll
        for (int nt = 0; nt < 2; nt++)
            #pragma unroll
            for (int r = 0; r < 16; r++) acc[mt][nt][r] = 0.f;

    int xb[2];
    #pragma unroll
    for (int nt = 0; nt < 2; nt++) {
        int pxl = nh * 64 + nt * 32 + l31;
        xb[nt] = ((pxl >> 3) * 10 + (pxl & 7)) * 136 + half * 8;
    }

    // A stream: Awt[(s*8 + mh*4 + mt)*512 + lane*8]
    const ushort* abase = Awt + (size_t)(mh * 4) * 512 + lane * 8;
    bf16x8 A0[4], A1[4], AN0[4], AN1[4];
    #pragma unroll
    for (int mt = 0; mt < 4; mt++) {
        A0[mt] = *(const bf16x8*)(abase + (size_t)mt * 512);
        A1[mt] = *(const bf16x8*)(abase + 4096 + (size_t)mt * 512);
    }

    #pragma unroll 1
    for (int s = 0; s < 72; s += 2) {
        if (s + 2 < 72) {
            #pragma unroll
            for (int mt = 0; mt < 4; mt++)
                AN0[mt] = *(const bf16x8*)(abase + (size_t)(s + 2) * 4096 + mt * 512);
        }
        {
            int tap = s >> 3, c16 = s & 7;
            int ky = tap / 3, kx = tap - ky * 3;
            int xoff = (ky * 10 + kx) * 136 + c16 * 16;
            bf16x8 b0 = *(const bf16x8*)&Xs[xb[0] + xoff];
            bf16x8 b1 = *(const bf16x8*)&Xs[xb[1] + xoff];
            #pragma unroll
            for (int mt = 0; mt < 4; mt++) {
                acc[mt][0] = __builtin_amdgcn_mfma_f32_32x32x16_bf16(A0[mt], b0, acc[mt][0], 0, 0, 0);
                acc[mt][1] = __builtin_amdgcn_mfma_f32_32x32x16_bf16(A0[mt], b1, acc[mt][1], 0, 0, 0);
            }
        }
        if (s + 3 < 72) {
            #pragma unroll
            for (int mt = 0; mt < 4; mt++)
                AN1[mt] = *(const bf16x8*)(abase + (size_t)(s + 3) * 4096 + mt * 512);
        }
        {
            int s1 = s + 1;
            int tap = s1 >> 3, c16 = s1 & 7;
            int ky = tap / 3, kx = tap - ky * 3;
            int xoff = (ky * 10 + kx) * 136 + c16 * 16;
            bf16x8 b0 = *(const bf16x8*)&Xs[xb[0] + xoff];
            bf16x8 b1 = *(const bf16x8*)&Xs[xb[1] + xoff];
            #pragma unroll
            for (int mt = 0; mt < 4; mt++) {
                acc[mt][0] = __builtin_amdgcn_mfma_f32_32x32x16_bf16(A1[mt], b0, acc[mt][0], 0, 0, 0);
                acc[mt][1] = __builtin_amdgcn_mfma_f32_32x32x16_bf16(A1[mt], b1, acc[mt][1], 0, 0, 0);
            }
        }
        #pragma unroll
        for (int mt = 0; mt < 4; mt++) { A0[mt] = AN0[mt]; A1[mt] = AN1[mt]; }
    }

    // epilogue: shuffle via LDS, two passes of 16x16 shuffled px x 64 ch
    const int S2 = 68;
    #pragma unroll 1
    for (int p = 0; p < 2; p++) {
        __syncthreads();
        if (nh == p) {
            #pragma unroll
            for (int nt = 0; nt < 2; nt++) {
                int pxl = nh * 64 + nt * 32 + l31;
                int rowl = pxl >> 3, coll = pxl & 7;
                int Y0 = 2 * (rowl - 8 * p), X0 = 2 * coll;
                #pragma unroll
                for (int mt = 0; mt < 4; mt++) {
                    #pragma unroll
                    for (int g = 0; g < 4; g++) {
                        int o = mh * 32 + mt * 8 + 2 * g + half;
                        #pragma unroll
                        for (int i = 0; i < 4; i++) {
                            int ry = (i >> 1), rx = i & 1;
                            Xs[((Y0 + ry) * 16 + X0 + rx) * S2 + o] =
                                f2bf(acc[mt][nt][g * 4 + i]);
                        }
                    }
                }
            }
        }
        __syncthreads();
        for (int idx = tid; idx < 4096; idx += 256) {
            int px = idx >> 4, q = idx & 15;
            ushort4 v = *(ushort4*)&Xs[px * S2 + q * 4];
            int Yg = tr * 32 + p * 16 + (px >> 4), Xg = tc * 16 + (px & 15);
            *(ushort4*)(U + ((size_t)((b * 128 + Yg) * 128 + Xg)) * 64 + q * 4) = v;
        }
    }
}

// ------ re1: conv3x3(U,re_w1)+relu via 16x16x32 MFMA -> R1[b,Y,X,8] ---------
__global__ __launch_bounds__(256, 2) void re1_kernel(const ushort* __restrict__ U,
                                                     const ushort* __restrict__ Aw1,
                                                     ushort* __restrict__ R1) {
    __shared__ ushort Xs[324 * 72];  // 46656 B
    __shared__ ushort As[18 * 64 * 8];
    const int b = blockIdx.y;
    const int ty = blockIdx.x >> 3, tx = blockIdx.x & 7;
    const int tid = threadIdx.x;
    const int wave = tid >> 6, lane = tid & 63;
    const int m16 = lane & 15, kq = lane >> 4;

    for (int idx = tid; idx < 1152; idx += 256)
        *(int4*)&As[idx * 8] = *(const int4*)(Aw1 + (size_t)idx * 8);
    for (int idx = tid; idx < 2592; idx += 256) {
        int px = idx >> 3, q = idx & 7;
        int r = px / 18, c = px - r * 18;
        int gY = ty * 16 - 1 + r, gX = tx * 16 - 1 + c;
        int4 v = {0, 0, 0, 0};
        if ((unsigned)gY < 128u && (unsigned)gX < 128u)
            v = *(const int4*)(U + ((size_t)((b * 128 + gY) * 128 + gX)) * 64 + q * 8);
        *(int4*)&Xs[px * 72 + q * 8] = v;
    }
    __syncthreads();

    f32x4 acc[4];
    #pragma unroll
    for (int nt = 0; nt < 4; nt++)
        #pragma unroll
        for (int r = 0; r < 4; r++) acc[nt][r] = 0.f;

    #pragma unroll 1
    for (int s = 0; s < 18; s++) {
        bf16x8 a = *(const bf16x8*)&As[(s * 64 + lane) * 8];
        int tap = s >> 1, ch = s & 1;
        int ky = tap / 3, kx = tap - ky * 3;
        int xo = (ky * 18 + kx) * 72 + ch * 32 + kq * 8;
        #pragma unroll
        for (int nt = 0; nt < 4; nt++) {
            int row = wave * 4 + nt;
            bf16x8 bv = *(const bf16x8*)&Xs[(row * 18 + m16) * 72 + xo];
            acc[nt] = __builtin_amdgcn_mfma_f32_16x16x32_bf16(a, bv, acc[nt], 0, 0, 0);
        }
    }
    if (kq < 2) {
        #pragma unroll
        for (int nt = 0; nt < 4; nt++) {
            int gY = ty * 16 + wave * 4 + nt, gX = tx * 16 + m16;
            ushort4 pk = {f2bf(fmaxf(acc[nt][0], 0.f)), f2bf(fmaxf(acc[nt][1], 0.f)),
                          f2bf(fmaxf(acc[nt][2], 0.f)), f2bf(fmaxf(acc[nt][3], 0.f))};
            *(ushort4*)(R1 + ((size_t)((b * 128 + gY) * 128 + gX)) * 8 + kq * 4) = pk;
        }
    }
}

// ------ re2: conv3x3(R1,re_w2) + up  via 32x32x16 MFMA -> out f32 planar ----
__global__ __launch_bounds__(256, 2) void re2_kernel(const ushort* __restrict__ R1,
                                                     const ushort* __restrict__ U,
                                                     const ushort* __restrict__ Aw2,
                                                     float* __restrict__ out) {
    __shared__ ushort Xs[324 * 8];   // 5184 B
    __shared__ ushort As[5 * 2 * 64 * 8];
    __shared__ ushort Us[256 * 68];  // 34816 B
    const int b = blockIdx.y;
    const int ty = blockIdx.x >> 3, tx = blockIdx.x & 7;
    const int tid = threadIdx.x;
    const int wave = tid >> 6, lane = tid & 63;
    const int l31 = lane & 31, half = lane >> 5;

    for (int idx = tid; idx < 640; idx += 256)
        *(int4*)&As[idx * 8] = *(const int4*)(Aw2 + (size_t)idx * 8);
    for (int idx = tid; idx < 324; idx += 256) {
        int r = idx / 18, c = idx - r * 18;
        int gY = ty * 16 - 1 + r, gX = tx * 16 - 1 + c;
        int4 v = {0, 0, 0, 0};
        if ((unsigned)gY < 128u && (unsigned)gX < 128u)
            v = *(const int4*)(R1 + ((size_t)((b * 128 + gY) * 128 + gX)) * 8);
        *(int4*)&Xs[idx * 8] = v;
    }
    for (int idx = tid; idx < 2048; idx += 256) {
        int px = idx >> 3, q = idx & 7;
        int gY = ty * 16 + (px >> 4), gX = tx * 16 + (px & 15);
        const ushort* s = U + ((size_t)((b * 128 + gY) * 128 + gX)) * 64 + q * 8;
        ushort4 v0 = *(const ushort4*)s;
        ushort4 v1 = *(const ushort4*)(s + 4);
        *(ushort4*)&Us[px * 68 + q * 8] = v0;
        *(ushort4*)&Us[px * 68 + q * 8 + 4] = v1;
    }
    __syncthreads();

    f32x16 acc[2][2];
    #pragma unroll
    for (int mt = 0; mt < 2; mt++)
        #pragma unroll
        for (int nt = 0; nt < 2; nt++)
            #pragma unroll
            for (int r = 0; r < 16; r++) acc[mt][nt][r] = 0.f;

    #pragma unroll
    for (int s = 0; s < 5; s++) {
        bf16x8 a0 = *(const bf16x8*)&As[((s * 2 + 0) * 64 + lane) * 8];
        bf16x8 a1 = *(const bf16x8*)&As[((s * 2 + 1) * 64 + lane) * 8];
        int t = 2 * s + half;
        if (t > 8) t = 8;  // A is zero there
        int ky = t / 3, kx = t - ky * 3;
        #pragma unroll
        for (int nt = 0; nt < 2; nt++) {
            int pxl = wave * 64 + nt * 32 + l31;
            int row = pxl >> 4, col = pxl & 15;
            bf16x8 bv = *(const bf16x8*)&Xs[((row + ky) * 18 + col + kx) * 8];
            acc[0][nt] = __builtin_amdgcn_mfma_f32_32x32x16_bf16(a0, bv, acc[0][nt], 0, 0, 0);
            acc[1][nt] = __builtin_amdgcn_mfma_f32_32x32x16_bf16(a1, bv, acc[1][nt], 0, 0, 0);
        }
    }
    #pragma unroll
    for (int mt = 0; mt < 2; mt++) {
        #pragma unroll
        for (int nt = 0; nt < 2; nt++) {
            int pxl = wave * 64 + nt * 32 + l31;
            int gY = ty * 16 + (pxl >> 4), gX = tx * 16 + (pxl & 15);
            #pragma unroll
            for (int r = 0; r < 16; r++) {
                int o = mt * 32 + (r & 3) + 8 * (r >> 2) + 4 * half;
                float v = acc[mt][nt][r] + bf2f(Us[pxl * 68 + o]);
                out[((size_t)(b * 64 + o) * 128 + gY) * 128 + gX] = v;
            }
        }
    }
}

extern "C" void kernel_launch(void* const* d_in, const int* in_sizes, int n_in,
                              void* d_out, int out_size, void* d_ws, size_t ws_size,
                              hipStream_t stream) {
    const float* x1      = (const float*)d_in[0];
    const float* x2      = (const float*)d_in[1];
    const float* d1_w1   = (const float*)d_in[2];
    const float* d1_w2   = (const float*)d_in[3];
    const float* d2_w1   = (const float*)d_in[4];
    const float* d2_w2   = (const float*)d_in[5];
    const float* align_w = (const float*)d_in[6];
    const float* up_w1   = (const float*)d_in[7];
    const float* up_w2   = (const float*)d_in[8];
    const float* re_w1   = (const float*)d_in[9];
    const float* re_w2   = (const float*)d_in[10];
    float* out = (float*)d_out;
    float* ws  = (float*)d_ws;

    float*  pooled = ws + OFF_POOLED;
    float*  wkb    = ws + OFF_WK;
    ushort* Awt    = (ushort*)(ws + OFF_WT);
    ushort* Wf     = (ushort*)(ws + OFF_WF);
    ushort* Aw1    = (ushort*)(ws + OFF_AW1);
    ushort* Aw2    = (ushort*)(ws + OFF_AW2);
    ushort* bufT   = (ushort*)(ws + OFF_T);
    ushort* R1     = (ushort*)(ws + OFF_T);   // alias (bufT dead by re1)
    ushort* bufAB  = (ushort*)(ws + OFF_AB);
    ushort* bufU   = (ushort*)(ws + OFF_AB);  // alias (bufAB dead after align)
    ushort* F      = (ushort*)(ws + OFF_F);

    wcomb_kernel<<<1152, 256, 0, stream>>>(up_w1, up_w2, Awt);
    awprep_kernel<<<1, 256, 0, stream>>>(align_w, Wf);
    aw1prep_kernel<<<36, 256, 0, stream>>>(re_w1, Aw1);
    aw2prep_kernel<<<20, 256, 0, stream>>>(re_w2, Aw2);

    pool_both_kernel<<<4096, 256, 0, stream>>>(x1, x2, pooled);
    wk_kernel<<<32, 128, 0, stream>>>(pooled, d1_w1, d1_w2, wkb);
    dsc1_kernel<<<4096, 256, 0, stream>>>(x1, x2, wkb, bufT, pooled);
    wk_kernel<<<32, 128, 0, stream>>>(pooled, d2_w1, d2_w2, wkb);
    dsc2_kernel<<<4096, 256, 0, stream>>>(bufT, wkb, bufAB);

    align_mfma_kernel<<<dim3(32, 16), 256, 0, stream>>>(bufAB, bufAB + 8388608, Wf, F);
    up_mfma_kernel<<<dim3(32, 16), 256, 0, stream>>>(F, Awt, bufU);
    re1_kernel<<<dim3(64, 16), 256, 0, stream>>>(bufU, Aw1, R1);
    re2_kernel<<<dim3(64, 16), 256, 0, stream>>>(R1, bufU, Aw2, out);
}